// Round 1
// baseline (4679.565 us; speedup 1.0000x reference)
//
#include <hip/hip_runtime.h>
#include <hip/hip_bf16.h>
#include <cstdio>
#include <cstdint>

// ---------------- model dims ----------------
#define E_    1280
#define L_    4
#define NH_   16
#define D_    80
#define MLP_  5120
#define O_    2048
#define S_    2048
#define SPP_  1024
#define H4_   5120
#define INP_  1536

typedef __attribute__((ext_vector_type(4))) float f32x4;
typedef __attribute__((ext_vector_type(8))) short short8v;
typedef __attribute__((ext_vector_type(4))) short short4v;

__device__ __forceinline__ short f2bf(float f){
  uint32_t u = __float_as_uint(f);
  uint32_t r = (u + 0x7FFFu + ((u >> 16) & 1u)) >> 16;   // RNE
  return (short)r;
}
__device__ __forceinline__ float bf2f(short s){
  return __uint_as_float(((uint32_t)(uint16_t)s) << 16);
}
__device__ __forceinline__ float gelu_tanh(float x){
  return 0.5f*x*(1.f + tanhf(0.7978845608028654f*(x + 0.044715f*x*x*x)));
}
__device__ __forceinline__ float gelu_erf(float x){
  return 0.5f*x*(1.f + erff(x*0.7071067811865476f));
}
// token -> (h,w) grid coords after the MS=2 window reorder
__device__ __forceinline__ void token_hw(int t, int& hc, int& wc){
  hc = ((t>>1)&1) + ((t>>6)<<1);
  wc = (t&1)      + (((t>>2)&15)<<1);
}

// ---------------- GEMM ----------------
// C[m][n] = epi( sum_k A[m][k]*B[n][k] + bias[n] ) (+ C residual)
// A: (M,K) row-major, B: (N,K) row-major (i.e. X @ W^T). bf16 MFMA, f32 accum.
// Optional batch over gridDim.z: z -> (h = z/nImg, img = z%nImg) pointer offsets.
struct GemmP {
  const void* A; const void* B; void* C;
  const float* bias;
  int lda, ldb, ldc;
  int M, N, K;
  float scale;
  long long aOffH, aOffI, bOffH, bOffI, cOffH, cOffI;
  int nImg;
};

template<bool F32>
__device__ __forceinline__ void stage_row(const void* base, long long bOff, int row,
                                          int ld, int K, int k0, int rowLim, short* dst)
{
  const bool rowOK = row < rowLim;
  if constexpr (F32) {
    const float* src = (const float*)base + bOff + (long long)row*ld;
    if (rowOK && (k0+32) <= K) {
      #pragma unroll
      for (int c=0;c<32;c+=8){
        float4 v0 = *(const float4*)(src+k0+c);
        float4 v1 = *(const float4*)(src+k0+c+4);
        short8v w;
        w[0]=f2bf(v0.x); w[1]=f2bf(v0.y); w[2]=f2bf(v0.z); w[3]=f2bf(v0.w);
        w[4]=f2bf(v1.x); w[5]=f2bf(v1.y); w[6]=f2bf(v1.z); w[7]=f2bf(v1.w);
        *(short8v*)(dst+c) = w;
      }
    } else {
      #pragma unroll
      for (int c=0;c<32;c+=8){
        short8v w;
        #pragma unroll
        for (int j=0;j<8;j++){
          float f = 0.f;
          if (rowOK && (k0+c+j) < K) f = src[k0+c+j];
          w[j] = f2bf(f);
        }
        *(short8v*)(dst+c) = w;
      }
    }
  } else {
    const short* src = (const short*)base + bOff + (long long)row*ld;
    if (rowOK && (k0+32) <= K) {
      #pragma unroll
      for (int c=0;c<32;c+=8)
        *(short8v*)(dst+c) = *(const short8v*)(src+k0+c);
    } else {
      #pragma unroll
      for (int c=0;c<32;c+=8){
        short8v w;
        #pragma unroll
        for (int j=0;j<8;j++){
          float f = 0.f;
          if (rowOK && (k0+c+j) < K) f = bf2f(src[k0+c+j]);
          w[j] = f2bf(f);
        }
        *(short8v*)(dst+c) = w;
      }
    }
  }
}

// EPI: 0=none, 1=gelu(tanh), 2=gelu(erf), 3=scale
template<bool AF32, bool BF32, int EPI, bool RES, bool CF32>
__global__ __launch_bounds__(256)
void gemm_k(GemmP p)
{
  __shared__ short As[128][48];
  __shared__ short Bs[128][48];

  const int z  = blockIdx.z;
  const int hI = z / p.nImg, iI = z % p.nImg;
  const long long aB = (long long)hI*p.aOffH + (long long)iI*p.aOffI;
  const long long bB = (long long)hI*p.bOffH + (long long)iI*p.bOffI;
  const long long cB = (long long)hI*p.cOffH + (long long)iI*p.cOffI;

  const int mt = blockIdx.y, nt = blockIdx.x;
  const int tid = threadIdx.x;
  const int wv = tid >> 6, lane = tid & 63;
  const int wr = (wv >> 1) * 64, wc = (wv & 1) * 64;
  const int fr = lane & 15, fo = (lane >> 4) * 8;

  const bool sB = tid >= 128;
  const int srow = tid & 127;

  f32x4 acc[4][4] = {};

  for (int k0 = 0; k0 < p.K; k0 += 32){
    if (!sB) stage_row<AF32>(p.A, aB, mt*128 + srow, p.lda, p.K, k0, p.M, &As[srow][0]);
    else     stage_row<BF32>(p.B, bB, nt*128 + srow, p.ldb, p.K, k0, p.N, &Bs[srow][0]);
    __syncthreads();
    short8v a[4], b[4];
    #pragma unroll
    for (int i=0;i<4;i++){
      a[i] = *(const short8v*)&As[wr + i*16 + fr][fo];
      b[i] = *(const short8v*)&Bs[wc + i*16 + fr][fo];
    }
    #pragma unroll
    for (int i=0;i<4;i++)
      #pragma unroll
      for (int j=0;j<4;j++)
        acc[i][j] = __builtin_amdgcn_mfma_f32_16x16x32_bf16(a[i], b[j], acc[i][j], 0, 0, 0);
    __syncthreads();
  }

  #pragma unroll
  for (int i=0;i<4;i++){
    #pragma unroll
    for (int j=0;j<4;j++){
      #pragma unroll
      for (int r=0;r<4;r++){
        const int row = mt*128 + wr + i*16 + (lane>>4)*4 + r;
        const int col = nt*128 + wc + j*16 + (lane&15);
        if (row < p.M && col < p.N){
          float v = acc[i][j][r];
          if (p.bias) v += p.bias[col];
          if constexpr (EPI==1) v = gelu_tanh(v);
          if constexpr (EPI==2) v = gelu_erf(v);
          if constexpr (EPI==3) v *= p.scale;
          const long long off = cB + (long long)row*p.ldc + col;
          if constexpr (RES)  v += ((const float*)p.C)[off];
          if constexpr (CF32) ((float*)p.C)[off] = v;
          else                ((short*)p.C)[off] = f2bf(v);
        }
      }
    }
  }
}

// ---------------- LayerNorm (f32 in, bf16 out) ----------------
__global__ __launch_bounds__(256)
void ln_k(const float* __restrict__ X, const float* __restrict__ g, const float* __restrict__ bta,
          short* __restrict__ Y, int Cn)
{
  __shared__ float red[8];
  const int row = blockIdx.x;
  const float* x = X + (long long)row*Cn;
  short* y = Y + (long long)row*Cn;
  float s = 0.f, sq = 0.f;
  for (int c = threadIdx.x*4; c < Cn; c += 1024){
    float4 v = *(const float4*)(x + c);
    s  += v.x+v.y+v.z+v.w;
    sq += v.x*v.x+v.y*v.y+v.z*v.z+v.w*v.w;
  }
  #pragma unroll
  for (int m=32;m;m>>=1){ s += __shfl_xor(s,m,64); sq += __shfl_xor(sq,m,64); }
  const int wv = threadIdx.x>>6, lane = threadIdx.x&63;
  if (lane==0){ red[wv]=s; red[4+wv]=sq; }
  __syncthreads();
  s  = red[0]+red[1]+red[2]+red[3];
  sq = red[4]+red[5]+red[6]+red[7];
  const float mean = s / (float)Cn;
  const float var  = sq / (float)Cn - mean*mean;
  const float rs   = rsqrtf(var + 1e-6f);
  for (int c = threadIdx.x*4; c < Cn; c += 1024){
    float4 v  = *(const float4*)(x + c);
    float4 gw = *(const float4*)(g + c);
    float4 bw = *(const float4*)(bta + c);
    short4v o;
    o[0] = f2bf((v.x-mean)*rs*gw.x + bw.x);
    o[1] = f2bf((v.y-mean)*rs*gw.y + bw.y);
    o[2] = f2bf((v.z-mean)*rs*gw.z + bw.z);
    o[3] = f2bf((v.w-mean)*rs*gw.w + bw.w);
    *(short4v*)(y + c) = o;
  }
}

// ---------------- softmax over rows of 1024, bf16 in-place ----------------
__global__ __launch_bounds__(256)
void softmax_k(short* __restrict__ P)
{
  __shared__ float red[8];
  const long long row = blockIdx.x;
  short* p = P + row*1024;
  const int tid = threadIdx.x;
  short4v raw = *(short4v*)(p + tid*4);
  float v0=bf2f(raw[0]), v1=bf2f(raw[1]), v2=bf2f(raw[2]), v3=bf2f(raw[3]);
  float mx = fmaxf(fmaxf(v0,v1), fmaxf(v2,v3));
  #pragma unroll
  for (int m=32;m;m>>=1) mx = fmaxf(mx, __shfl_xor(mx,m,64));
  const int wv = tid>>6, lane = tid&63;
  if (lane==0) red[wv]=mx;
  __syncthreads();
  mx = fmaxf(fmaxf(red[0],red[1]), fmaxf(red[2],red[3]));
  __syncthreads();
  v0 = expf(v0-mx); v1 = expf(v1-mx); v2 = expf(v2-mx); v3 = expf(v3-mx);
  float s = v0+v1+v2+v3;
  #pragma unroll
  for (int m=32;m;m>>=1) s += __shfl_xor(s,m,64);
  if (lane==0) red[4+wv]=s;
  __syncthreads();
  s = red[4]+red[5]+red[6]+red[7];
  const float inv = 1.f / s;
  short4v o; o[0]=f2bf(v0*inv); o[1]=f2bf(v1*inv); o[2]=f2bf(v2*inv); o[3]=f2bf(v3*inv);
  *(short4v*)(p + tid*4) = o;
}

// ---------------- rope + head layout (q,k roped; v transposed) ----------------
__global__ __launch_bounds__(256)
void rope_k(const float* __restrict__ qkv, short* __restrict__ qh,
            short* __restrict__ kh, short* __restrict__ vt)
{
  const int idx = blockIdx.x*256 + threadIdx.x;     // over S*NH*40
  if (idx >= S_*NH_*40) return;
  const int d0 = idx % 40;
  const int h  = (idx / 40) % NH_;
  const int s  = idx / (40*NH_);
  const int t  = s & 1023, img = s >> 10;
  int hc, wc; token_hw(t, hc, wc);
  const int j  = d0 % 20;
  const float invf = exp2f(-0.66438561897747f * (float)j);   // 10000^(-j/20)
  const float pos  = (float)((d0 < 20) ? hc : wc);
  const float f = pos * invf;
  float sn, cs; sincosf(f, &sn, &cs);
  const float* base = qkv + (long long)s*3840 + h*80;
  const float q1 = base[d0],      q2 = base[d0+40];
  const float k1 = base[1280+d0], k2 = base[1280+d0+40];
  const float v1 = base[2560+d0], v2 = base[2560+d0+40];
  const long long qo = ((long long)h*S_ + s)*80;
  qh[qo + d0]    = f2bf(q1*cs - q2*sn);
  qh[qo + d0+40] = f2bf(q2*cs + q1*sn);
  kh[qo + d0]    = f2bf(k1*cs - k2*sn);
  kh[qo + d0+40] = f2bf(k2*cs + k1*sn);
  const long long vo = (((long long)h*2 + img)*80)*1024 + t;
  vt[vo + (long long)d0*1024]      = f2bf(v1);
  vt[vo + (long long)(d0+40)*1024] = f2bf(v2);
}

// ---------------- pos-embed bilinear interpolation add ----------------
__global__ __launch_bounds__(256)
void posadd_k(float* __restrict__ h, const float* __restrict__ pe)
{
  const int idx = blockIdx.x*256 + threadIdx.x;     // over S*(E/4)
  if (idx >= S_*(E_/4)) return;
  const int c4 = idx % (E_/4), s = idx / (E_/4);
  const int e = c4*4;
  const int t = s & 1023;
  int hc, wc; token_hw(t, hc, wc);
  const float hi = (float)hc * (47.f/31.f);
  const float wi = (float)wc * (47.f/31.f);
  int hf = (int)hi; float dh = hi - (float)hf; int h2 = min(hf+1, 47);
  int wf = (int)wi; float dw = wi - (float)wf; int w2 = min(wf+1, 47);
  const float w00=(1.f-dh)*(1.f-dw), w01=(1.f-dh)*dw, w10=dh*(1.f-dw), w11=dh*dw;
  const float4 a = *(const float4*)(pe + ((long long)(hf*48+wf))*E_ + e);
  const float4 b = *(const float4*)(pe + ((long long)(hf*48+w2))*E_ + e);
  const float4 c = *(const float4*)(pe + ((long long)(h2*48+wf))*E_ + e);
  const float4 d = *(const float4*)(pe + ((long long)(h2*48+w2))*E_ + e);
  float* out = h + (long long)s*E_ + e;
  float4 o = *(float4*)out;
  o.x += w00*a.x + w01*b.x + w10*c.x + w11*d.x;
  o.y += w00*a.y + w01*b.y + w10*c.y + w11*d.y;
  o.z += w00*a.z + w01*b.z + w10*c.z + w11*d.z;
  o.w += w00*a.w + w01*b.w + w10*c.w + w11*d.w;
  *(float4*)out = o;
}

// ---------------- host side ----------------
static GemmP mk(const void* A, const void* B, void* C, const float* bias,
                int lda, int ldb, int ldc, int M, int N, int K, float scale = 1.f)
{
  GemmP p{}; p.A=A; p.B=B; p.C=C; p.bias=bias;
  p.lda=lda; p.ldb=ldb; p.ldc=ldc; p.M=M; p.N=N; p.K=K; p.scale=scale;
  p.aOffH=p.aOffI=p.bOffH=p.bOffI=p.cOffH=p.cOffI=0; p.nImg=1;
  return p;
}

extern "C" void kernel_launch(void* const* d_in, const int* in_sizes, int n_in,
                              void* d_out, int out_size, void* d_ws, size_t ws_size,
                              hipStream_t stream)
{
  const float* x           = (const float*)d_in[0];
  const float* patch_w     = (const float*)d_in[1];
  const float* patch_b     = (const float*)d_in[2];
  const float* pos_emb     = (const float*)d_in[3];
  const float* ln1_w       = (const float*)d_in[4];
  const float* ln1_b       = (const float*)d_in[5];
  const float* ln2_w       = (const float*)d_in[6];
  const float* ln2_b       = (const float*)d_in[7];
  const float* qkv_w       = (const float*)d_in[8];
  const float* qkv_b       = (const float*)d_in[9];
  const float* attn_proj_w = (const float*)d_in[10];
  const float* attn_proj_b = (const float*)d_in[11];
  const float* fc1_w       = (const float*)d_in[12];
  const float* fc1_b       = (const float*)d_in[13];
  const float* fc2_w       = (const float*)d_in[14];
  const float* fc2_b       = (const float*)d_in[15];
  const float* m_ln_w      = (const float*)d_in[16];
  const float* m_ln_b      = (const float*)d_in[17];
  const float* m_fc1_w     = (const float*)d_in[18];
  const float* m_fc1_b     = (const float*)d_in[19];
  const float* m_fc2_w     = (const float*)d_in[20];
  const float* m_fc2_b     = (const float*)d_in[21];
  const float* ds_ln_w     = (const float*)d_in[22];
  const float* ds_ln_b     = (const float*)d_in[23];
  const float* ds_fc1_w    = (const float*)d_in[24];
  const float* ds_fc1_b    = (const float*)d_in[25];
  const float* ds_fc2_w    = (const float*)d_in[26];
  const float* ds_fc2_b    = (const float*)d_in[27];
  float* out = (float*)d_out;

  char* wsp = (char*)d_ws;
  auto alloc = [&](size_t bytes)->char*{
    char* p = wsp; wsp += (bytes + 255) & ~(size_t)255; return p;
  };
  float* h   = (float*)alloc((size_t)S_*E_*4);          // residual stream (f32)
  float* qkv = (float*)alloc((size_t)S_*3840*4);        // qkv proj out (f32)
  short* aln = (short*)alloc((size_t)S_*E_*2);          // LN out (bf16), also 512x5120 merger LN
  short* qh  = (short*)alloc((size_t)NH_*S_*D_*2);      // [NH][S][80]
  short* kh  = (short*)alloc((size_t)NH_*S_*D_*2);
  short* vt  = (short*)alloc((size_t)NH_*2*D_*1024*2);  // [NH][img][80][1024]
  short* p   = (short*)alloc((size_t)NH_*S_*1024*2);    // scores/probs bf16 [NH][img][1024][1024]
  short* o2  = (short*)alloc((size_t)S_*E_*2);          // attn out, token-major (bf16)
  short* ffn = (short*)alloc((size_t)S_*MLP_*2);        // gelu(fc1) out (bf16), also merger mid
  size_t need = (size_t)(wsp - (char*)d_ws);
  if (need > ws_size){
    fprintf(stderr, "kernel_launch: ws too small: need %zu have %zu\n", need, ws_size);
    return;
  }

  auto G = [](int M, int N){ return dim3((unsigned)((N+127)/128), (unsigned)((M+127)/128), 1); };
  const dim3 B256(256);

  // patch embed: h = x @ patch_w^T + patch_b
  { GemmP pp = mk(x, patch_w, h, patch_b, INP_, INP_, E_, S_, E_, INP_);
    gemm_k<true,true,0,false,true><<<G(S_,E_),B256,0,stream>>>(pp); }
  posadd_k<<<(S_*(E_/4)+255)/256, B256, 0, stream>>>(h, pos_emb);

  for (int l = 0; l < L_; l++){
    // attention
    ln_k<<<S_, B256, 0, stream>>>(h, ln1_w + l*E_, ln1_b + l*E_, aln, E_);
    { GemmP pp = mk(aln, qkv_w + (size_t)l*3840*E_, qkv, qkv_b + l*3840, E_, E_, 3840, S_, 3840, E_);
      gemm_k<false,true,0,false,true><<<G(S_,3840),B256,0,stream>>>(pp); }
    rope_k<<<(S_*NH_*40+255)/256, B256, 0, stream>>>(qkv, qh, kh, vt);
    { GemmP pp = mk(qh, kh, p, nullptr, D_, D_, 1024, 1024, 1024, D_, 0.11180339887498949f);
      pp.aOffH=(long long)S_*D_; pp.aOffI=(long long)1024*D_;
      pp.bOffH=(long long)S_*D_; pp.bOffI=(long long)1024*D_;
      pp.cOffH=(long long)S_*1024; pp.cOffI=(long long)1024*1024; pp.nImg=2;
      gemm_k<false,false,3,false,false><<<dim3(8,8,32),B256,0,stream>>>(pp); }
    softmax_k<<<NH_*S_, B256, 0, stream>>>(p);
    { GemmP pp = mk(p, vt, o2, nullptr, 1024, 1024, E_, 1024, D_, 1024);
      pp.aOffH=(long long)S_*1024; pp.aOffI=(long long)1024*1024;
      pp.bOffH=(long long)2*D_*1024; pp.bOffI=(long long)D_*1024;
      pp.cOffH=D_; pp.cOffI=(long long)1024*E_; pp.nImg=2;
      gemm_k<false,false,0,false,false><<<dim3(1,8,32),B256,0,stream>>>(pp); }
    { GemmP pp = mk(o2, attn_proj_w + (size_t)l*E_*E_, h, attn_proj_b + l*E_, E_, E_, E_, S_, E_, E_);
      gemm_k<false,true,0,true,true><<<G(S_,E_),B256,0,stream>>>(pp); }

    // MLP
    ln_k<<<S_, B256, 0, stream>>>(h, ln2_w + l*E_, ln2_b + l*E_, aln, E_);
    { GemmP pp = mk(aln, fc1_w + (size_t)l*MLP_*E_, ffn, fc1_b + l*MLP_, E_, E_, MLP_, S_, MLP_, E_);
      gemm_k<false,true,1,false,false><<<G(S_,MLP_),B256,0,stream>>>(pp); }
    { GemmP pp = mk(ffn, fc2_w + (size_t)l*E_*MLP_, h, fc2_b + l*E_, MLP_, MLP_, E_, S_, E_, MLP_);
      gemm_k<false,true,0,true,true><<<G(S_,E_),B256,0,stream>>>(pp); }

    // deepstack mergers after layers 1 and 2 (post=True: reshape then LN over 5120)
    if (l == 1 || l == 2){
      const int j = l - 1;
      ln_k<<<512, B256, 0, stream>>>(h, ds_ln_w + (size_t)j*H4_, ds_ln_b + (size_t)j*H4_, aln, H4_);
      { GemmP pp = mk(aln, ds_fc1_w + (size_t)j*H4_*H4_, ffn, ds_fc1_b + (size_t)j*H4_,
                      H4_, H4_, H4_, 512, H4_, H4_);
        gemm_k<false,true,2,false,false><<<G(512,H4_),B256,0,stream>>>(pp); }
      { GemmP pp = mk(ffn, ds_fc2_w + (size_t)j*O_*H4_, out + (size_t)(1+j)*512*O_,
                      ds_fc2_b + (size_t)j*O_, H4_, H4_, O_, 512, O_, H4_);
        gemm_k<false,true,0,false,true><<<G(512,O_),B256,0,stream>>>(pp); }
    }
  }

  // main merger (post=False: LN over 1280, then reshape to 512x5120)
  ln_k<<<S_, B256, 0, stream>>>(h, m_ln_w, m_ln_b, aln, E_);
  { GemmP pp = mk(aln, m_fc1_w, ffn, m_fc1_b, H4_, H4_, H4_, 512, H4_, H4_);
    gemm_k<false,true,2,false,false><<<G(512,H4_),B256,0,stream>>>(pp); }
  { GemmP pp = mk(ffn, m_fc2_w, out, m_fc2_b, H4_, H4_, O_, 512, O_, H4_);
    gemm_k<false,true,0,false,true><<<G(512,O_),B256,0,stream>>>(pp); }
}

// Round 2
// 2998.922 us; speedup vs baseline: 1.5604x; 1.5604x over previous
//
#include <hip/hip_runtime.h>
#include <hip/hip_bf16.h>
#include <cstdio>
#include <cstdint>

// ---------------- model dims ----------------
#define E_    1280
#define L_    4
#define NH_   16
#define D_    80
#define DP_   96      // D padded to mult of 32 for QK^T K-loop
#define MLP_  5120
#define O_    2048
#define S_    2048
#define H4_   5120
#define INP_  1536

typedef __attribute__((ext_vector_type(4))) float f32x4;
typedef __attribute__((ext_vector_type(8))) short short8v;
typedef __attribute__((ext_vector_type(4))) short short4v;

__device__ __forceinline__ short f2bf(float f){
  uint32_t u = __float_as_uint(f);
  uint32_t r = (u + 0x7FFFu + ((u >> 16) & 1u)) >> 16;   // RNE
  return (short)r;
}
__device__ __forceinline__ float bf2f(short s){
  return __uint_as_float(((uint32_t)(uint16_t)s) << 16);
}
__device__ __forceinline__ float gelu_tanh(float x){
  return 0.5f*x*(1.f + tanhf(0.7978845608028654f*(x + 0.044715f*x*x*x)));
}
__device__ __forceinline__ float gelu_erf(float x){
  return 0.5f*x*(1.f + erff(x*0.7071067811865476f));
}
// token -> (h,w) grid coords after the MS=2 window reorder
__device__ __forceinline__ void token_hw(int t, int& hc, int& wc){
  hc = ((t>>1)&1) + ((t>>6)<<1);
  wc = (t&1)      + (((t>>2)&15)<<1);
}

// async global->LDS, 16B per lane; lds dest is wave-uniform base + lane*16
__device__ __forceinline__ void gload16(const short* g, short* l){
  __builtin_amdgcn_global_load_lds((const __attribute__((address_space(1))) void*)g,
                                   (__attribute__((address_space(3))) void*)l, 16, 0, 0);
}

// ---------------- f32 -> bf16 bulk convert ----------------
__global__ __launch_bounds__(256)
void cvt_k(const float* __restrict__ src, short* __restrict__ dst, long long n)
{
  const long long stride = (long long)gridDim.x*256*8;
  for (long long i = ((long long)blockIdx.x*256 + threadIdx.x)*8; i < n; i += stride){
    if (i + 8 <= n){
      float4 v0 = *(const float4*)(src+i);
      float4 v1 = *(const float4*)(src+i+4);
      short8v w;
      w[0]=f2bf(v0.x); w[1]=f2bf(v0.y); w[2]=f2bf(v0.z); w[3]=f2bf(v0.w);
      w[4]=f2bf(v1.x); w[5]=f2bf(v1.y); w[6]=f2bf(v1.z); w[7]=f2bf(v1.w);
      *(short8v*)(dst+i) = w;
    } else {
      for (long long j=i;j<n;j++) dst[j] = f2bf(src[j]);
    }
  }
}

// ---------------- GEMM v2: bf16 A,B via global_load_lds ----------------
// C[m][n] = epi( sum_k A[m][k]*B[n][k] + bias[n] ) (+ residual from C)
// A:(M,K) row-major bf16, B:(N,K) row-major bf16. K % 32 == 0.
// Out-of-range rows are clamped (values land only in discarded output cols/rows).
struct Gemm2P {
  const short* A; const short* B; void* C;
  const float* bias;
  int lda, ldb, ldc, M, N, K;
  float scale;
  long long aOffH, aOffI, bOffH, bOffI, cOffH, cOffI;
  int nImg;
};

template<int EPI, bool RES, bool CF32>   // EPI: 0=none,1=gelu_tanh,2=gelu_erf,3=scale
__global__ __launch_bounds__(256)
void gemm2_k(Gemm2P p)
{
  __shared__ short As[128*32];
  __shared__ short Bs[128*32];

  const int z  = blockIdx.z;
  const int hI = z / p.nImg, iI = z % p.nImg;
  const long long aB = (long long)hI*p.aOffH + (long long)iI*p.aOffI;
  const long long bB = (long long)hI*p.bOffH + (long long)iI*p.bOffI;
  const long long cB = (long long)hI*p.cOffH + (long long)iI*p.cOffI;

  const int mt = blockIdx.y, nt = blockIdx.x;
  const int tid = threadIdx.x, lane = tid & 63, wv = tid >> 6;

  // staging: wave wv owns segments (wv*2, wv*2+1) of each 8KB tile.
  // segment s covers rows s*16..s*16+15; lane l -> row s*16 + l/4, kcol (l%4)*8
  const int sr = lane >> 2;
  const int sc = (lane & 3) * 8;
  int ra0 = mt*128 + (wv*2+0)*16 + sr; if (ra0 >= p.M) ra0 = p.M-1;
  int ra1 = mt*128 + (wv*2+1)*16 + sr; if (ra1 >= p.M) ra1 = p.M-1;
  int rb0 = nt*128 + (wv*2+0)*16 + sr; if (rb0 >= p.N) rb0 = p.N-1;
  int rb1 = nt*128 + (wv*2+1)*16 + sr; if (rb1 >= p.N) rb1 = p.N-1;
  const short* pa0 = p.A + aB + (long long)ra0*p.lda + sc;
  const short* pa1 = p.A + aB + (long long)ra1*p.lda + sc;
  const short* pb0 = p.B + bB + (long long)rb0*p.ldb + sc;
  const short* pb1 = p.B + bB + (long long)rb1*p.ldb + sc;
  short* la0 = &As[(wv*2+0)*512];
  short* la1 = &As[(wv*2+1)*512];
  short* lb0 = &Bs[(wv*2+0)*512];
  short* lb1 = &Bs[(wv*2+1)*512];

  const int fr = lane & 15, fo = (lane >> 4) * 8;
  const int wr = (wv >> 1) * 64, wc = (wv & 1) * 64;

  f32x4 acc[4][4] = {};

  for (int k0 = 0; k0 < p.K; k0 += 32){
    gload16(pa0 + k0, la0);
    gload16(pa1 + k0, la1);
    gload16(pb0 + k0, lb0);
    gload16(pb1 + k0, lb1);
    __syncthreads();             // drains vmcnt before barrier
    short8v a[4], b[4];
    #pragma unroll
    for (int i=0;i<4;i++){
      a[i] = *(const short8v*)&As[(wr + i*16 + fr)*32 + fo];
      b[i] = *(const short8v*)&Bs[(wc + i*16 + fr)*32 + fo];
    }
    #pragma unroll
    for (int i=0;i<4;i++)
      #pragma unroll
      for (int j=0;j<4;j++)
        acc[i][j] = __builtin_amdgcn_mfma_f32_16x16x32_bf16(a[i], b[j], acc[i][j], 0, 0, 0);
    __syncthreads();
  }

  #pragma unroll
  for (int i=0;i<4;i++){
    #pragma unroll
    for (int j=0;j<4;j++){
      #pragma unroll
      for (int r=0;r<4;r++){
        const int row = mt*128 + wr + i*16 + (lane>>4)*4 + r;
        const int col = nt*128 + wc + j*16 + fr;
        if (row < p.M && col < p.N){
          float v = acc[i][j][r];
          if (p.bias) v += p.bias[col];
          if constexpr (EPI==1) v = gelu_tanh(v);
          if constexpr (EPI==2) v = gelu_erf(v);
          if constexpr (EPI==3) v *= p.scale;
          const long long off = cB + (long long)row*p.ldc + col;
          if constexpr (RES)  v += ((const float*)p.C)[off];
          if constexpr (CF32) ((float*)p.C)[off] = v;
          else                ((short*)p.C)[off] = f2bf(v);
        }
      }
    }
  }
}

// ---------------- LayerNorm (f32 in, bf16 out) ----------------
__global__ __launch_bounds__(256)
void ln_k(const float* __restrict__ X, const float* __restrict__ g, const float* __restrict__ bta,
          short* __restrict__ Y, int Cn)
{
  __shared__ float red[8];
  const int row = blockIdx.x;
  const float* x = X + (long long)row*Cn;
  short* y = Y + (long long)row*Cn;
  float s = 0.f, sq = 0.f;
  for (int c = threadIdx.x*4; c < Cn; c += 1024){
    float4 v = *(const float4*)(x + c);
    s  += v.x+v.y+v.z+v.w;
    sq += v.x*v.x+v.y*v.y+v.z*v.z+v.w*v.w;
  }
  #pragma unroll
  for (int m=32;m;m>>=1){ s += __shfl_xor(s,m,64); sq += __shfl_xor(sq,m,64); }
  const int wv = threadIdx.x>>6, lane = threadIdx.x&63;
  if (lane==0){ red[wv]=s; red[4+wv]=sq; }
  __syncthreads();
  s  = red[0]+red[1]+red[2]+red[3];
  sq = red[4]+red[5]+red[6]+red[7];
  const float mean = s / (float)Cn;
  const float var  = sq / (float)Cn - mean*mean;
  const float rs   = rsqrtf(var + 1e-6f);
  for (int c = threadIdx.x*4; c < Cn; c += 1024){
    float4 v  = *(const float4*)(x + c);
    float4 gw = *(const float4*)(g + c);
    float4 bw = *(const float4*)(bta + c);
    short4v o;
    o[0] = f2bf((v.x-mean)*rs*gw.x + bw.x);
    o[1] = f2bf((v.y-mean)*rs*gw.y + bw.y);
    o[2] = f2bf((v.z-mean)*rs*gw.z + bw.z);
    o[3] = f2bf((v.w-mean)*rs*gw.w + bw.w);
    *(short4v*)(y + c) = o;
  }
}

// ---------------- softmax over rows of 1024, bf16 in-place ----------------
__global__ __launch_bounds__(256)
void softmax_k(short* __restrict__ P)
{
  __shared__ float red[8];
  const long long row = blockIdx.x;
  short* p = P + row*1024;
  const int tid = threadIdx.x;
  short4v raw = *(short4v*)(p + tid*4);
  float v0=bf2f(raw[0]), v1=bf2f(raw[1]), v2=bf2f(raw[2]), v3=bf2f(raw[3]);
  float mx = fmaxf(fmaxf(v0,v1), fmaxf(v2,v3));
  #pragma unroll
  for (int m=32;m;m>>=1) mx = fmaxf(mx, __shfl_xor(mx,m,64));
  const int wv = tid>>6, lane = tid&63;
  if (lane==0) red[wv]=mx;
  __syncthreads();
  mx = fmaxf(fmaxf(red[0],red[1]), fmaxf(red[2],red[3]));
  __syncthreads();
  v0 = expf(v0-mx); v1 = expf(v1-mx); v2 = expf(v2-mx); v3 = expf(v3-mx);
  float s = v0+v1+v2+v3;
  #pragma unroll
  for (int m=32;m;m>>=1) s += __shfl_xor(s,m,64);
  if (lane==0) red[4+wv]=s;
  __syncthreads();
  s = red[4]+red[5]+red[6]+red[7];
  const float inv = 1.f / s;
  short4v o; o[0]=f2bf(v0*inv); o[1]=f2bf(v1*inv); o[2]=f2bf(v2*inv); o[3]=f2bf(v3*inv);
  *(short4v*)(p + tid*4) = o;
}

// ---------------- rope + head layout (bf16 qkv in) ----------------
// qh/kh: [NH][S][96] (cols 80..95 zero-padded); vt: [NH][img][80][1024]
__global__ __launch_bounds__(256)
void rope_k(const short* __restrict__ qkv, short* __restrict__ qh,
            short* __restrict__ kh, short* __restrict__ vt)
{
  const int idx = blockIdx.x*256 + threadIdx.x;     // over S*NH*40
  if (idx >= S_*NH_*40) return;
  const int d0 = idx % 40;
  const int h  = (idx / 40) % NH_;
  const int s  = idx / (40*NH_);
  const int t  = s & 1023, img = s >> 10;
  int hc, wc; token_hw(t, hc, wc);
  const int j  = d0 % 20;
  const float invf = exp2f(-0.66438561897747f * (float)j);   // 10000^(-j/20)
  const float pos  = (float)((d0 < 20) ? hc : wc);
  float sn, cs; sincosf(pos * invf, &sn, &cs);
  const short* base = qkv + (long long)s*3840 + h*80;
  const float q1 = bf2f(base[d0]),      q2 = bf2f(base[d0+40]);
  const float k1 = bf2f(base[1280+d0]), k2 = bf2f(base[1280+d0+40]);
  const long long qo = ((long long)h*S_ + s)*DP_;
  qh[qo + d0]    = f2bf(q1*cs - q2*sn);
  qh[qo + d0+40] = f2bf(q2*cs + q1*sn);
  kh[qo + d0]    = f2bf(k1*cs - k2*sn);
  kh[qo + d0+40] = f2bf(k2*cs + k1*sn);
  if (d0 < 16){ qh[qo + 80 + d0] = 0; kh[qo + 80 + d0] = 0; }
  const long long vo = (((long long)h*2 + img)*80)*1024 + t;
  vt[vo + (long long)d0*1024]      = base[2560+d0];
  vt[vo + (long long)(d0+40)*1024] = base[2560+d0+40];
}

// ---------------- pos-embed bilinear interpolation add ----------------
__global__ __launch_bounds__(256)
void posadd_k(float* __restrict__ h, const float* __restrict__ pe)
{
  const int idx = blockIdx.x*256 + threadIdx.x;     // over S*(E/4)
  if (idx >= S_*(E_/4)) return;
  const int c4 = idx % (E_/4), s = idx / (E_/4);
  const int e = c4*4;
  const int t = s & 1023;
  int hc, wc; token_hw(t, hc, wc);
  const float hi = (float)hc * (47.f/31.f);
  const float wi = (float)wc * (47.f/31.f);
  int hf = (int)hi; float dh = hi - (float)hf; int h2 = min(hf+1, 47);
  int wf = (int)wi; float dw = wi - (float)wf; int w2 = min(wf+1, 47);
  const float w00=(1.f-dh)*(1.f-dw), w01=(1.f-dh)*dw, w10=dh*(1.f-dw), w11=dh*dw;
  const float4 a = *(const float4*)(pe + ((long long)(hf*48+wf))*E_ + e);
  const float4 b = *(const float4*)(pe + ((long long)(hf*48+w2))*E_ + e);
  const float4 c = *(const float4*)(pe + ((long long)(h2*48+wf))*E_ + e);
  const float4 d = *(const float4*)(pe + ((long long)(h2*48+w2))*E_ + e);
  float* out = h + (long long)s*E_ + e;
  float4 o = *(float4*)out;
  o.x += w00*a.x + w01*b.x + w10*c.x + w11*d.x;
  o.y += w00*a.y + w01*b.y + w10*c.y + w11*d.y;
  o.z += w00*a.z + w01*b.z + w10*c.z + w11*d.z;
  o.w += w00*a.w + w01*b.w + w10*c.w + w11*d.w;
  *(float4*)out = o;
}

// ---------------- host side ----------------
static Gemm2P mk(const short* A, const short* B, void* C, const float* bias,
                 int lda, int ldb, int ldc, int M, int N, int K, float scale = 1.f)
{
  Gemm2P p{}; p.A=A; p.B=B; p.C=C; p.bias=bias;
  p.lda=lda; p.ldb=ldb; p.ldc=ldc; p.M=M; p.N=N; p.K=K; p.scale=scale;
  p.aOffH=p.aOffI=p.bOffH=p.bOffI=p.cOffH=p.cOffI=0; p.nImg=1;
  return p;
}

extern "C" void kernel_launch(void* const* d_in, const int* in_sizes, int n_in,
                              void* d_out, int out_size, void* d_ws, size_t ws_size,
                              hipStream_t stream)
{
  const float* x           = (const float*)d_in[0];
  const float* patch_w     = (const float*)d_in[1];
  const float* patch_b     = (const float*)d_in[2];
  const float* pos_emb     = (const float*)d_in[3];
  const float* ln1_w       = (const float*)d_in[4];
  const float* ln1_b       = (const float*)d_in[5];
  const float* ln2_w       = (const float*)d_in[6];
  const float* ln2_b       = (const float*)d_in[7];
  const float* qkv_w       = (const float*)d_in[8];
  const float* qkv_b       = (const float*)d_in[9];
  const float* attn_proj_w = (const float*)d_in[10];
  const float* attn_proj_b = (const float*)d_in[11];
  const float* fc1_w       = (const float*)d_in[12];
  const float* fc1_b       = (const float*)d_in[13];
  const float* fc2_w       = (const float*)d_in[14];
  const float* fc2_b       = (const float*)d_in[15];
  const float* m_ln_w      = (const float*)d_in[16];
  const float* m_ln_b      = (const float*)d_in[17];
  const float* m_fc1_w     = (const float*)d_in[18];
  const float* m_fc1_b     = (const float*)d_in[19];
  const float* m_fc2_w     = (const float*)d_in[20];
  const float* m_fc2_b     = (const float*)d_in[21];
  const float* ds_ln_w     = (const float*)d_in[22];
  const float* ds_ln_b     = (const float*)d_in[23];
  const float* ds_fc1_w    = (const float*)d_in[24];
  const float* ds_fc1_b    = (const float*)d_in[25];
  const float* ds_fc2_w    = (const float*)d_in[26];
  const float* ds_fc2_b    = (const float*)d_in[27];
  float* out = (float*)d_out;

  char* wsp = (char*)d_ws;
  auto alloc = [&](size_t bytes)->char*{
    char* p = wsp; wsp += (bytes + 255) & ~(size_t)255; return p;
  };
  // activations
  float* h    = (float*)alloc((size_t)S_*E_*4);         // residual stream (f32)
  short* qkvb = (short*)alloc((size_t)S_*3840*2);       // qkv proj out (bf16)
  short* aln  = (short*)alloc((size_t)S_*E_*2);         // LN out (bf16); merger LN reuses
  short* qh   = (short*)alloc((size_t)NH_*S_*DP_*2);    // [NH][S][96]
  short* kh   = (short*)alloc((size_t)NH_*S_*DP_*2);
  short* vt   = (short*)alloc((size_t)NH_*2*D_*1024*2); // [NH][img][80][1024]
  short* p    = (short*)alloc((size_t)NH_*S_*1024*2);   // scores/probs [NH][img][1024][1024]
  short* o2   = (short*)alloc((size_t)S_*E_*2);         // attn out token-major (bf16)
  short* ffn  = (short*)alloc((size_t)S_*MLP_*2);       // gelu(fc1) out; merger mid reuses
  // bf16 weight cache
  short* xb    = (short*)alloc((size_t)S_*INP_*2);
  short* pwB   = (short*)alloc((size_t)E_*INP_*2);
  short* qkvwB = (short*)alloc((size_t)L_*3840*E_*2);
  short* prwB  = (short*)alloc((size_t)L_*E_*E_*2);
  short* f1wB  = (short*)alloc((size_t)L_*MLP_*E_*2);
  short* f2wB  = (short*)alloc((size_t)L_*E_*MLP_*2);
  short* mf1B  = (short*)alloc((size_t)H4_*H4_*2);
  short* mf2B  = (short*)alloc((size_t)O_*H4_*2);
  short* df1B  = (short*)alloc((size_t)2*H4_*H4_*2);
  short* df2B  = (short*)alloc((size_t)2*O_*H4_*2);
  size_t need = (size_t)(wsp - (char*)d_ws);
  if (need > ws_size){
    fprintf(stderr, "kernel_launch: ws too small: need %zu have %zu\n", need, ws_size);
    return;
  }

  const dim3 B256(256);
  auto cvt = [&](const float* src, short* dst, long long n){
    unsigned blk = (unsigned)min((long long)8192, (n/8 + 255)/256);
    cvt_k<<<blk, B256, 0, stream>>>(src, dst, n);
  };
  cvt(x, xb, (long long)S_*INP_);
  cvt(patch_w, pwB, (long long)E_*INP_);
  cvt(qkv_w, qkvwB, (long long)L_*3840*E_);
  cvt(attn_proj_w, prwB, (long long)L_*E_*E_);
  cvt(fc1_w, f1wB, (long long)L_*MLP_*E_);
  cvt(fc2_w, f2wB, (long long)L_*E_*MLP_);
  cvt(m_fc1_w, mf1B, (long long)H4_*H4_);
  cvt(m_fc2_w, mf2B, (long long)O_*H4_);
  cvt(ds_fc1_w, df1B, (long long)2*H4_*H4_);
  cvt(ds_fc2_w, df2B, (long long)2*O_*H4_);

  auto G = [](int M, int N){ return dim3((unsigned)((N+127)/128), (unsigned)((M+127)/128), 1); };

  // patch embed: h = x @ patch_w^T + patch_b
  { Gemm2P pp = mk(xb, pwB, h, patch_b, INP_, INP_, E_, S_, E_, INP_);
    gemm2_k<0,false,true><<<G(S_,E_),B256,0,stream>>>(pp); }
  posadd_k<<<(S_*(E_/4)+255)/256, B256, 0, stream>>>(h, pos_emb);

  for (int l = 0; l < L_; l++){
    // attention
    ln_k<<<S_, B256, 0, stream>>>(h, ln1_w + l*E_, ln1_b + l*E_, aln, E_);
    { Gemm2P pp = mk(aln, qkvwB + (size_t)l*3840*E_, qkvb, qkv_b + l*3840, E_, E_, 3840, S_, 3840, E_);
      gemm2_k<0,false,false><<<G(S_,3840),B256,0,stream>>>(pp); }
    rope_k<<<(S_*NH_*40+255)/256, B256, 0, stream>>>(qkvb, qh, kh, vt);
    { Gemm2P pp = mk(qh, kh, p, nullptr, DP_, DP_, 1024, 1024, 1024, DP_, 0.11180339887498949f);
      pp.aOffH=(long long)S_*DP_; pp.aOffI=(long long)1024*DP_;
      pp.bOffH=(long long)S_*DP_; pp.bOffI=(long long)1024*DP_;
      pp.cOffH=(long long)S_*1024; pp.cOffI=(long long)1024*1024; pp.nImg=2;
      gemm2_k<3,false,false><<<dim3(8,8,32),B256,0,stream>>>(pp); }
    softmax_k<<<NH_*S_, B256, 0, stream>>>(p);
    { Gemm2P pp = mk(p, vt, o2, nullptr, 1024, 1024, E_, 1024, D_, 1024);
      pp.aOffH=(long long)S_*1024; pp.aOffI=(long long)1024*1024;
      pp.bOffH=(long long)2*D_*1024; pp.bOffI=(long long)D_*1024;
      pp.cOffH=D_; pp.cOffI=(long long)1024*E_; pp.nImg=2;
      gemm2_k<0,false,false><<<dim3(1,8,32),B256,0,stream>>>(pp); }
    { Gemm2P pp = mk(o2, prwB + (size_t)l*E_*E_, h, attn_proj_b + l*E_, E_, E_, E_, S_, E_, E_);
      gemm2_k<0,true,true><<<G(S_,E_),B256,0,stream>>>(pp); }

    // MLP
    ln_k<<<S_, B256, 0, stream>>>(h, ln2_w + l*E_, ln2_b + l*E_, aln, E_);
    { Gemm2P pp = mk(aln, f1wB + (size_t)l*MLP_*E_, ffn, fc1_b + l*MLP_, E_, E_, MLP_, S_, MLP_, E_);
      gemm2_k<1,false,false><<<G(S_,MLP_),B256,0,stream>>>(pp); }
    { Gemm2P pp = mk(ffn, f2wB + (size_t)l*E_*MLP_, h, fc2_b + l*E_, MLP_, MLP_, E_, S_, E_, MLP_);
      gemm2_k<0,true,true><<<G(S_,E_),B256,0,stream>>>(pp); }

    // deepstack mergers after layers 1 and 2 (post=True: reshape then LN over 5120)
    if (l == 1 || l == 2){
      const int j = l - 1;
      ln_k<<<512, B256, 0, stream>>>(h, ds_ln_w + (size_t)j*H4_, ds_ln_b + (size_t)j*H4_, aln, H4_);
      { Gemm2P pp = mk(aln, df1B + (size_t)j*H4_*H4_, ffn, ds_fc1_b + (size_t)j*H4_,
                       H4_, H4_, H4_, 512, H4_, H4_);
        gemm2_k<2,false,false><<<G(512,H4_),B256,0,stream>>>(pp); }
      { Gemm2P pp = mk(ffn, df2B + (size_t)j*O_*H4_, out + (size_t)(1+j)*512*O_,
                       ds_fc2_b + (size_t)j*O_, H4_, H4_, O_, 512, O_, H4_);
        gemm2_k<0,false,true><<<G(512,O_),B256,0,stream>>>(pp); }
    }
  }

  // main merger (post=False: LN over 1280, then reshape to 512x5120)
  ln_k<<<S_, B256, 0, stream>>>(h, m_ln_w, m_ln_b, aln, E_);
  { Gemm2P pp = mk(aln, mf1B, ffn, m_fc1_b, H4_, H4_, H4_, 512, H4_, H4_);
    gemm2_k<2,false,false><<<G(512,H4_),B256,0,stream>>>(pp); }
  { Gemm2P pp = mk(ffn, mf2B, out, m_fc2_b, H4_, H4_, O_, 512, O_, H4_);
    gemm2_k<0,false,true><<<G(512,O_),B256,0,stream>>>(pp); }
}

// Round 3
// 1805.290 us; speedup vs baseline: 2.5921x; 1.6612x over previous
//
#include <hip/hip_runtime.h>
#include <hip/hip_bf16.h>
#include <cstdio>
#include <cstdint>

// ---------------- model dims ----------------
#define E_    1280
#define L_    4
#define NH_   16
#define D_    80
#define DP_   96      // D padded to mult of 32 for QK^T K-loop
#define MLP_  5120
#define O_    2048
#define S_    2048
#define H4_   5120
#define INP_  1536

typedef __attribute__((ext_vector_type(4))) float f32x4;
typedef __attribute__((ext_vector_type(8))) short short8v;
typedef __attribute__((ext_vector_type(4))) short short4v;

__device__ __forceinline__ short f2bf(float f){
  uint32_t u = __float_as_uint(f);
  uint32_t r = (u + 0x7FFFu + ((u >> 16) & 1u)) >> 16;   // RNE
  return (short)r;
}
__device__ __forceinline__ float bf2f(short s){
  return __uint_as_float(((uint32_t)(uint16_t)s) << 16);
}
__device__ __forceinline__ float gelu_tanh(float x){
  return 0.5f*x*(1.f + tanhf(0.7978845608028654f*(x + 0.044715f*x*x*x)));
}
__device__ __forceinline__ float gelu_erf(float x){
  return 0.5f*x*(1.f + erff(x*0.7071067811865476f));
}
// token -> (h,w) grid coords after the MS=2 window reorder
__device__ __forceinline__ void token_hw(int t, int& hc, int& wc){
  hc = ((t>>1)&1) + ((t>>6)<<1);
  wc = (t&1)      + (((t>>2)&15)<<1);
}

// async global->LDS, 16B per lane; lds dest is wave-uniform base + lane*16
__device__ __forceinline__ void gload16(const short* g, short* l){
  __builtin_amdgcn_global_load_lds((const __attribute__((address_space(1))) void*)g,
                                   (__attribute__((address_space(3))) void*)l, 16, 0, 0);
}

// ---------------- f32 -> bf16 bulk convert ----------------
__global__ __launch_bounds__(256)
void cvt_k(const float* __restrict__ src, short* __restrict__ dst, long long n)
{
  const long long stride = (long long)gridDim.x*256*8;
  for (long long i = ((long long)blockIdx.x*256 + threadIdx.x)*8; i < n; i += stride){
    if (i + 8 <= n){
      float4 v0 = *(const float4*)(src+i);
      float4 v1 = *(const float4*)(src+i+4);
      short8v w;
      w[0]=f2bf(v0.x); w[1]=f2bf(v0.y); w[2]=f2bf(v0.z); w[3]=f2bf(v0.w);
      w[4]=f2bf(v1.x); w[5]=f2bf(v1.y); w[6]=f2bf(v1.z); w[7]=f2bf(v1.w);
      *(short8v*)(dst+i) = w;
    } else {
      for (long long j=i;j<n;j++) dst[j] = f2bf(src[j]);
    }
  }
}

// ---------------- GEMM v3: bf16, 2-phase prefetch, optional split-K ----------------
// C[m][n] = epi( sum_k A[m][k]*B[n][k] + bias[n] ) (+ residual from C)
// A:(M,K) bf16 row-major, B:(N,K) bf16 row-major. K % 32 == 0 (and % (32*kSplit) for split).
struct Gemm2P {
  const short* A; const short* B; void* C;
  const float* bias;
  float* part;                  // split-K partial buffer [kSplit][M][N] f32
  int lda, ldb, ldc, M, N, K;
  float scale;
  long long aOffH, aOffI, bOffH, bOffI, cOffH, cOffI;
  int nImg, kSplit;
};

template<int EPI, bool RES, bool CF32, bool SPLIT>   // EPI: 0=none,1=gelu_tanh,2=gelu_erf,3=scale
__global__ __launch_bounds__(256)
void gemm2_k(Gemm2P p)
{
  __shared__ short As[2][4096];   // [buf][128*32]
  __shared__ short Bs[2][4096];

  int z = blockIdx.z, ks = 0;
  if constexpr (SPLIT){ ks = z % p.kSplit; z /= p.kSplit; }
  const int hI = z / p.nImg, iI = z % p.nImg;
  const long long aB = (long long)hI*p.aOffH + (long long)iI*p.aOffI;
  const long long bB = (long long)hI*p.bOffH + (long long)iI*p.bOffI;
  const long long cB = (long long)hI*p.cOffH + (long long)iI*p.cOffI;

  // bijective XCD swizzle on the tile plane (m204)
  const int nwg = gridDim.x*gridDim.y;
  const int orig = blockIdx.y*gridDim.x + blockIdx.x;
  const int q8 = nwg >> 3, r8 = nwg & 7;
  const int xcd = orig & 7, oidx = orig >> 3;
  const int wg = (xcd < r8 ? xcd*(q8+1) : r8*(q8+1) + (xcd-r8)*q8) + oidx;
  const int nt = wg % gridDim.x, mt = wg / gridDim.x;

  const int tid = threadIdx.x, lane = tid & 63, wv = tid >> 6;

  // staging: wave wv owns segments (wv*2, wv*2+1); lane l -> row s*16 + l/4, col (l%4)*8
  const int sr = lane >> 2;
  const int sc = (lane & 3) * 8;
  const int Kp  = SPLIT ? p.K / p.kSplit : p.K;
  const int kBeg = SPLIT ? ks * Kp : 0;
  int ra0 = mt*128 + (wv*2+0)*16 + sr; if (ra0 >= p.M) ra0 = p.M-1;
  int ra1 = mt*128 + (wv*2+1)*16 + sr; if (ra1 >= p.M) ra1 = p.M-1;
  int rb0 = nt*128 + (wv*2+0)*16 + sr; if (rb0 >= p.N) rb0 = p.N-1;
  int rb1 = nt*128 + (wv*2+1)*16 + sr; if (rb1 >= p.N) rb1 = p.N-1;
  const short* pa0 = p.A + aB + (long long)ra0*p.lda + sc + kBeg;
  const short* pa1 = p.A + aB + (long long)ra1*p.lda + sc + kBeg;
  const short* pb0 = p.B + bB + (long long)rb0*p.ldb + sc + kBeg;
  const short* pb1 = p.B + bB + (long long)rb1*p.ldb + sc + kBeg;
  const int so0 = (wv*2+0)*512;
  const int so1 = (wv*2+1)*512;

  const int fr = lane & 15, fo = (lane >> 4) * 8;
  const int wr = (wv >> 1) * 64, wc = (wv & 1) * 64;

  f32x4 acc[4][4] = {};

  auto stage = [&](int buf, int k0){
    gload16(pa0 + k0, &As[buf][so0]);
    gload16(pa1 + k0, &As[buf][so1]);
    gload16(pb0 + k0, &Bs[buf][so0]);
    gload16(pb1 + k0, &Bs[buf][so1]);
  };

  const int ntile = Kp >> 5;
  stage(0, 0);
  __syncthreads();
  for (int t = 0; t < ntile; t++){
    const int cur = t & 1;
    if (t + 1 < ntile) stage(cur ^ 1, (t+1) << 5);   // prefetch overlaps this tile's compute
    short8v a[4], b[4];
    #pragma unroll
    for (int i=0;i<4;i++){
      a[i] = *(const short8v*)&As[cur][(wr + i*16 + fr)*32 + fo];
      b[i] = *(const short8v*)&Bs[cur][(wc + i*16 + fr)*32 + fo];
    }
    #pragma unroll
    for (int i=0;i<4;i++)
      #pragma unroll
      for (int j=0;j<4;j++)
        acc[i][j] = __builtin_amdgcn_mfma_f32_16x16x32_bf16(a[i], b[j], acc[i][j], 0, 0, 0);
    __syncthreads();   // drains vmcnt (prefetched tile ready) + lgkm
  }

  #pragma unroll
  for (int i=0;i<4;i++){
    #pragma unroll
    for (int j=0;j<4;j++){
      #pragma unroll
      for (int r=0;r<4;r++){
        const int row = mt*128 + wr + i*16 + (lane>>4)*4 + r;
        const int col = nt*128 + wc + j*16 + fr;
        if (row < p.M && col < p.N){
          float v = acc[i][j][r];
          if constexpr (SPLIT){
            p.part[((long long)ks*p.M + row)*p.N + col] = v;   // raw partial
          } else {
            if (p.bias) v += p.bias[col];
            if constexpr (EPI==1) v = gelu_tanh(v);
            if constexpr (EPI==2) v = gelu_erf(v);
            if constexpr (EPI==3) v *= p.scale;
            const long long off = cB + (long long)row*p.ldc + col;
            if constexpr (RES)  v += ((const float*)p.C)[off];
            if constexpr (CF32) ((float*)p.C)[off] = v;
            else                ((short*)p.C)[off] = f2bf(v);
          }
        }
      }
    }
  }
}

// ---------------- split-K reduce (C contiguous, ldc == N) ----------------
template<int EPI, bool RES, bool CF32>
__global__ __launch_bounds__(256)
void reduce_k(const float* __restrict__ part, int kSplit, long long MN, int N,
              const float* __restrict__ bias, void* __restrict__ C)
{
  const long long i = ((long long)blockIdx.x*256 + threadIdx.x)*4;
  if (i >= MN) return;
  float4 s = *(const float4*)(part + i);
  for (int ks = 1; ks < kSplit; ks++){
    const float4 v = *(const float4*)(part + (long long)ks*MN + i);
    s.x += v.x; s.y += v.y; s.z += v.z; s.w += v.w;
  }
  if (bias){
    const int col = (int)(i % N);
    const float4 b = *(const float4*)(bias + col);
    s.x += b.x; s.y += b.y; s.z += b.z; s.w += b.w;
  }
  if constexpr (EPI==1){ s.x=gelu_tanh(s.x); s.y=gelu_tanh(s.y); s.z=gelu_tanh(s.z); s.w=gelu_tanh(s.w); }
  if constexpr (EPI==2){ s.x=gelu_erf(s.x);  s.y=gelu_erf(s.y);  s.z=gelu_erf(s.z);  s.w=gelu_erf(s.w); }
  if constexpr (RES){
    const float4 r = *(const float4*)((const float*)C + i);
    s.x += r.x; s.y += r.y; s.z += r.z; s.w += r.w;
  }
  if constexpr (CF32){
    *(float4*)((float*)C + i) = s;
  } else {
    short4v o; o[0]=f2bf(s.x); o[1]=f2bf(s.y); o[2]=f2bf(s.z); o[3]=f2bf(s.w);
    *(short4v*)((short*)C + i) = o;
  }
}

// ---------------- LayerNorm (f32 in, bf16 out) ----------------
__global__ __launch_bounds__(256)
void ln_k(const float* __restrict__ X, const float* __restrict__ g, const float* __restrict__ bta,
          short* __restrict__ Y, int Cn)
{
  __shared__ float red[8];
  const int row = blockIdx.x;
  const float* x = X + (long long)row*Cn;
  short* y = Y + (long long)row*Cn;
  float s = 0.f, sq = 0.f;
  for (int c = threadIdx.x*4; c < Cn; c += 1024){
    float4 v = *(const float4*)(x + c);
    s  += v.x+v.y+v.z+v.w;
    sq += v.x*v.x+v.y*v.y+v.z*v.z+v.w*v.w;
  }
  #pragma unroll
  for (int m=32;m;m>>=1){ s += __shfl_xor(s,m,64); sq += __shfl_xor(sq,m,64); }
  const int wv = threadIdx.x>>6, lane = threadIdx.x&63;
  if (lane==0){ red[wv]=s; red[4+wv]=sq; }
  __syncthreads();
  s  = red[0]+red[1]+red[2]+red[3];
  sq = red[4]+red[5]+red[6]+red[7];
  const float mean = s / (float)Cn;
  const float var  = sq / (float)Cn - mean*mean;
  const float rs   = rsqrtf(var + 1e-6f);
  for (int c = threadIdx.x*4; c < Cn; c += 1024){
    float4 v  = *(const float4*)(x + c);
    float4 gw = *(const float4*)(g + c);
    float4 bw = *(const float4*)(bta + c);
    short4v o;
    o[0] = f2bf((v.x-mean)*rs*gw.x + bw.x);
    o[1] = f2bf((v.y-mean)*rs*gw.y + bw.y);
    o[2] = f2bf((v.z-mean)*rs*gw.z + bw.z);
    o[3] = f2bf((v.w-mean)*rs*gw.w + bw.w);
    *(short4v*)(y + c) = o;
  }
}

// ---------------- softmax over rows of 1024, bf16 in-place ----------------
__global__ __launch_bounds__(256)
void softmax_k(short* __restrict__ P)
{
  __shared__ float red[8];
  const long long row = blockIdx.x;
  short* p = P + row*1024;
  const int tid = threadIdx.x;
  short4v raw = *(short4v*)(p + tid*4);
  float v0=bf2f(raw[0]), v1=bf2f(raw[1]), v2=bf2f(raw[2]), v3=bf2f(raw[3]);
  float mx = fmaxf(fmaxf(v0,v1), fmaxf(v2,v3));
  #pragma unroll
  for (int m=32;m;m>>=1) mx = fmaxf(mx, __shfl_xor(mx,m,64));
  const int wv = tid>>6, lane = tid&63;
  if (lane==0) red[wv]=mx;
  __syncthreads();
  mx = fmaxf(fmaxf(red[0],red[1]), fmaxf(red[2],red[3]));
  __syncthreads();
  v0 = expf(v0-mx); v1 = expf(v1-mx); v2 = expf(v2-mx); v3 = expf(v3-mx);
  float s = v0+v1+v2+v3;
  #pragma unroll
  for (int m=32;m;m>>=1) s += __shfl_xor(s,m,64);
  if (lane==0) red[4+wv]=s;
  __syncthreads();
  s = red[4]+red[5]+red[6]+red[7];
  const float inv = 1.f / s;
  short4v o; o[0]=f2bf(v0*inv); o[1]=f2bf(v1*inv); o[2]=f2bf(v2*inv); o[3]=f2bf(v3*inv);
  *(short4v*)(p + tid*4) = o;
}

// ---------------- rope + head layout (bf16 qkv in) ----------------
// qh/kh: [NH][S][96] (cols 80..95 zero-padded); vt: [NH][img][80][1024]
__global__ __launch_bounds__(256)
void rope_k(const short* __restrict__ qkv, short* __restrict__ qh,
            short* __restrict__ kh, short* __restrict__ vt)
{
  const int idx = blockIdx.x*256 + threadIdx.x;     // over S*NH*40
  if (idx >= S_*NH_*40) return;
  const int d0 = idx % 40;
  const int h  = (idx / 40) % NH_;
  const int s  = idx / (40*NH_);
  const int t  = s & 1023, img = s >> 10;
  int hc, wc; token_hw(t, hc, wc);
  const int j  = d0 % 20;
  const float invf = exp2f(-0.66438561897747f * (float)j);   // 10000^(-j/20)
  const float pos  = (float)((d0 < 20) ? hc : wc);
  float sn, cs; sincosf(pos * invf, &sn, &cs);
  const short* base = qkv + (long long)s*3840 + h*80;
  const float q1 = bf2f(base[d0]),      q2 = bf2f(base[d0+40]);
  const float k1 = bf2f(base[1280+d0]), k2 = bf2f(base[1280+d0+40]);
  const long long qo = ((long long)h*S_ + s)*DP_;
  qh[qo + d0]    = f2bf(q1*cs - q2*sn);
  qh[qo + d0+40] = f2bf(q2*cs + q1*sn);
  kh[qo + d0]    = f2bf(k1*cs - k2*sn);
  kh[qo + d0+40] = f2bf(k2*cs + k1*sn);
  if (d0 < 16){ qh[qo + 80 + d0] = 0; kh[qo + 80 + d0] = 0; }
  const long long vo = (((long long)h*2 + img)*80)*1024 + t;
  vt[vo + (long long)d0*1024]      = base[2560+d0];
  vt[vo + (long long)(d0+40)*1024] = base[2560+d0+40];
}

// ---------------- pos-embed bilinear interpolation add ----------------
__global__ __launch_bounds__(256)
void posadd_k(float* __restrict__ h, const float* __restrict__ pe)
{
  const int idx = blockIdx.x*256 + threadIdx.x;     // over S*(E/4)
  if (idx >= S_*(E_/4)) return;
  const int c4 = idx % (E_/4), s = idx / (E_/4);
  const int e = c4*4;
  const int t = s & 1023;
  int hc, wc; token_hw(t, hc, wc);
  const float hi = (float)hc * (47.f/31.f);
  const float wi = (float)wc * (47.f/31.f);
  int hf = (int)hi; float dh = hi - (float)hf; int h2 = min(hf+1, 47);
  int wf = (int)wi; float dw = wi - (float)wf; int w2 = min(wf+1, 47);
  const float w00=(1.f-dh)*(1.f-dw), w01=(1.f-dh)*dw, w10=dh*(1.f-dw), w11=dh*dw;
  const float4 a = *(const float4*)(pe + ((long long)(hf*48+wf))*E_ + e);
  const float4 b = *(const float4*)(pe + ((long long)(hf*48+w2))*E_ + e);
  const float4 c = *(const float4*)(pe + ((long long)(h2*48+wf))*E_ + e);
  const float4 d = *(const float4*)(pe + ((long long)(h2*48+w2))*E_ + e);
  float* out = h + (long long)s*E_ + e;
  float4 o = *(float4*)out;
  o.x += w00*a.x + w01*b.x + w10*c.x + w11*d.x;
  o.y += w00*a.y + w01*b.y + w10*c.y + w11*d.y;
  o.z += w00*a.z + w01*b.z + w10*c.z + w11*d.z;
  o.w += w00*a.w + w01*b.w + w10*c.w + w11*d.w;
  *(float4*)out = o;
}

// ---------------- host side ----------------
static Gemm2P mk(const short* A, const short* B, void* C, const float* bias,
                 int lda, int ldb, int ldc, int M, int N, int K, float scale = 1.f)
{
  Gemm2P p{}; p.A=A; p.B=B; p.C=C; p.bias=bias; p.part=nullptr;
  p.lda=lda; p.ldb=ldb; p.ldc=ldc; p.M=M; p.N=N; p.K=K; p.scale=scale;
  p.aOffH=p.aOffI=p.bOffH=p.bOffI=p.cOffH=p.cOffI=0; p.nImg=1; p.kSplit=1;
  return p;
}

extern "C" void kernel_launch(void* const* d_in, const int* in_sizes, int n_in,
                              void* d_out, int out_size, void* d_ws, size_t ws_size,
                              hipStream_t stream)
{
  const float* x           = (const float*)d_in[0];
  const float* patch_w     = (const float*)d_in[1];
  const float* patch_b     = (const float*)d_in[2];
  const float* pos_emb     = (const float*)d_in[3];
  const float* ln1_w       = (const float*)d_in[4];
  const float* ln1_b       = (const float*)d_in[5];
  const float* ln2_w       = (const float*)d_in[6];
  const float* ln2_b       = (const float*)d_in[7];
  const float* qkv_w       = (const float*)d_in[8];
  const float* qkv_b       = (const float*)d_in[9];
  const float* attn_proj_w = (const float*)d_in[10];
  const float* attn_proj_b = (const float*)d_in[11];
  const float* fc1_w       = (const float*)d_in[12];
  const float* fc1_b       = (const float*)d_in[13];
  const float* fc2_w       = (const float*)d_in[14];
  const float* fc2_b       = (const float*)d_in[15];
  const float* m_ln_w      = (const float*)d_in[16];
  const float* m_ln_b      = (const float*)d_in[17];
  const float* m_fc1_w     = (const float*)d_in[18];
  const float* m_fc1_b     = (const float*)d_in[19];
  const float* m_fc2_w     = (const float*)d_in[20];
  const float* m_fc2_b     = (const float*)d_in[21];
  const float* ds_ln_w     = (const float*)d_in[22];
  const float* ds_ln_b     = (const float*)d_in[23];
  const float* ds_fc1_w    = (const float*)d_in[24];
  const float* ds_fc1_b    = (const float*)d_in[25];
  const float* ds_fc2_w    = (const float*)d_in[26];
  const float* ds_fc2_b    = (const float*)d_in[27];
  float* out = (float*)d_out;

  char* wsp = (char*)d_ws;
  auto alloc = [&](size_t bytes)->char*{
    char* p = wsp; wsp += (bytes + 255) & ~(size_t)255; return p;
  };
  // activations
  float* h    = (float*)alloc((size_t)S_*E_*4);         // residual stream (f32)
  short* qkvb = (short*)alloc((size_t)S_*3840*2);       // qkv proj out (bf16)
  short* aln  = (short*)alloc((size_t)S_*E_*2);         // LN out (bf16); merger LN reuses
  short* qh   = (short*)alloc((size_t)NH_*S_*DP_*2);    // [NH][S][96]
  short* kh   = (short*)alloc((size_t)NH_*S_*DP_*2);
  short* vt   = (short*)alloc((size_t)NH_*2*D_*1024*2); // [NH][img][80][1024]
  short* p    = (short*)alloc((size_t)NH_*S_*1024*2);   // scores [NH][img][1024][1024]; 64MB
  short* o2   = (short*)alloc((size_t)S_*E_*2);         // attn out token-major (bf16)
  short* ffn  = (short*)alloc((size_t)S_*MLP_*2);       // gelu(fc1) out; merger mid reuses
  // bf16 weight cache
  short* xb    = (short*)alloc((size_t)S_*INP_*2);
  short* pwB   = (short*)alloc((size_t)E_*INP_*2);
  short* qkvwB = (short*)alloc((size_t)L_*3840*E_*2);
  short* prwB  = (short*)alloc((size_t)L_*E_*E_*2);
  short* f1wB  = (short*)alloc((size_t)L_*MLP_*E_*2);
  short* f2wB  = (short*)alloc((size_t)L_*E_*MLP_*2);
  short* mf1B  = (short*)alloc((size_t)H4_*H4_*2);
  short* mf2B  = (short*)alloc((size_t)O_*H4_*2);
  short* df1B  = (short*)alloc((size_t)2*H4_*H4_*2);
  short* df2B  = (short*)alloc((size_t)2*O_*H4_*2);
  size_t need = (size_t)(wsp - (char*)d_ws);
  if (need > ws_size){
    fprintf(stderr, "kernel_launch: ws too small: need %zu have %zu\n", need, ws_size);
    return;
  }
  // split-K partials alias the score buffer (idle whenever a split GEMM runs)
  float* part = (float*)p;   // capacity 64MB; max use 4*2048*1280*4 = 41.9MB

  const dim3 B256(256);
  auto cvt = [&](const float* src, short* dst, long long n){
    unsigned blk = (unsigned)min((long long)8192, (n/8 + 255)/256);
    cvt_k<<<blk, B256, 0, stream>>>(src, dst, n);
  };
  cvt(x, xb, (long long)S_*INP_);
  cvt(patch_w, pwB, (long long)E_*INP_);
  cvt(qkv_w, qkvwB, (long long)L_*3840*E_);
  cvt(attn_proj_w, prwB, (long long)L_*E_*E_);
  cvt(fc1_w, f1wB, (long long)L_*MLP_*E_);
  cvt(fc2_w, f2wB, (long long)L_*E_*MLP_);
  cvt(m_fc1_w, mf1B, (long long)H4_*H4_);
  cvt(m_fc2_w, mf2B, (long long)O_*H4_);
  cvt(ds_fc1_w, df1B, (long long)2*H4_*H4_);
  cvt(ds_fc2_w, df2B, (long long)2*O_*H4_);

  auto G = [](int M, int N, int ks = 1){
    return dim3((unsigned)((N+127)/128), (unsigned)((M+127)/128), (unsigned)ks);
  };
  auto RG = [](long long MN){ return dim3((unsigned)((MN/4 + 255)/256)); };

  // patch embed: h = x @ patch_w^T + patch_b   (split-K x4: 160 -> 640 blocks)
  { Gemm2P pp = mk(xb, pwB, h, nullptr, INP_, INP_, E_, S_, E_, INP_);
    pp.part = part; pp.kSplit = 4;
    gemm2_k<0,false,true,true><<<G(S_,E_,4),B256,0,stream>>>(pp);
    reduce_k<0,false,true><<<RG((long long)S_*E_),B256,0,stream>>>(part, 4, (long long)S_*E_, E_, patch_b, h); }
  posadd_k<<<(S_*(E_/4)+255)/256, B256, 0, stream>>>(h, pos_emb);

  for (int l = 0; l < L_; l++){
    // attention
    ln_k<<<S_, B256, 0, stream>>>(h, ln1_w + l*E_, ln1_b + l*E_, aln, E_);
    { Gemm2P pp = mk(aln, qkvwB + (size_t)l*3840*E_, qkvb, qkv_b + l*3840, E_, E_, 3840, S_, 3840, E_);
      gemm2_k<0,false,false,false><<<G(S_,3840),B256,0,stream>>>(pp); }
    rope_k<<<(S_*NH_*40+255)/256, B256, 0, stream>>>(qkvb, qh, kh, vt);
    { Gemm2P pp = mk(qh, kh, p, nullptr, DP_, DP_, 1024, 1024, 1024, DP_, 0.11180339887498949f);
      pp.aOffH=(long long)S_*DP_; pp.aOffI=(long long)1024*DP_;
      pp.bOffH=(long long)S_*DP_; pp.bOffI=(long long)1024*DP_;
      pp.cOffH=(long long)S_*1024; pp.cOffI=(long long)1024*1024; pp.nImg=2;
      gemm2_k<3,false,false,false><<<dim3(8,8,32),B256,0,stream>>>(pp); }
    softmax_k<<<NH_*S_, B256, 0, stream>>>(p);
    { Gemm2P pp = mk(p, vt, o2, nullptr, 1024, 1024, E_, 1024, D_, 1024);
      pp.aOffH=(long long)S_*1024; pp.aOffI=(long long)1024*1024;
      pp.bOffH=(long long)2*D_*1024; pp.bOffI=(long long)D_*1024;
      pp.cOffH=D_; pp.cOffI=(long long)1024*E_; pp.nImg=2;
      gemm2_k<0,false,false,false><<<dim3(1,8,32),B256,0,stream>>>(pp); }
    // attn proj (+residual): split-K x4 (p is free now)
    { Gemm2P pp = mk(o2, prwB + (size_t)l*E_*E_, h, nullptr, E_, E_, E_, S_, E_, E_);
      pp.part = part; pp.kSplit = 4;
      gemm2_k<0,false,true,true><<<G(S_,E_,4),B256,0,stream>>>(pp);
      reduce_k<0,true,true><<<RG((long long)S_*E_),B256,0,stream>>>(part, 4, (long long)S_*E_, E_, attn_proj_b + l*E_, h); }

    // MLP
    ln_k<<<S_, B256, 0, stream>>>(h, ln2_w + l*E_, ln2_b + l*E_, aln, E_);
    { Gemm2P pp = mk(aln, f1wB + (size_t)l*MLP_*E_, ffn, fc1_b + l*MLP_, E_, E_, MLP_, S_, MLP_, E_);
      gemm2_k<1,false,false,false><<<G(S_,MLP_),B256,0,stream>>>(pp); }
    // fc2 (+residual): split-K x4
    { Gemm2P pp = mk(ffn, f2wB + (size_t)l*E_*MLP_, h, nullptr, MLP_, MLP_, E_, S_, E_, MLP_);
      pp.part = part; pp.kSplit = 4;
      gemm2_k<0,false,true,true><<<G(S_,E_,4),B256,0,stream>>>(pp);
      reduce_k<0,true,true><<<RG((long long)S_*E_),B256,0,stream>>>(part, 4, (long long)S_*E_, E_, fc2_b + l*E_, h); }

    // deepstack mergers after layers 1 and 2 (post=True: reshape then LN over 5120)
    if (l == 1 || l == 2){
      const int j = l - 1;
      ln_k<<<512, B256, 0, stream>>>(h, ds_ln_w + (size_t)j*H4_, ds_ln_b + (size_t)j*H4_, aln, H4_);
      { Gemm2P pp = mk(aln, df1B + (size_t)j*H4_*H4_, ffn, nullptr, H4_, H4_, H4_, 512, H4_, H4_);
        pp.part = part; pp.kSplit = 4;
        gemm2_k<0,false,false,true><<<G(512,H4_,4),B256,0,stream>>>(pp);
        reduce_k<2,false,false><<<RG((long long)512*H4_),B256,0,stream>>>(part, 4, (long long)512*H4_, H4_, ds_fc1_b + (size_t)j*H4_, ffn); }
      { Gemm2P pp = mk(ffn, df2B + (size_t)j*O_*H4_, out + (size_t)(1+j)*512*O_, nullptr, H4_, H4_, O_, 512, O_, H4_);
        pp.part = part; pp.kSplit = 8;
        gemm2_k<0,false,true,true><<<G(512,O_,8),B256,0,stream>>>(pp);
        reduce_k<0,false,true><<<RG((long long)512*O_),B256,0,stream>>>(part, 8, (long long)512*O_, O_, ds_fc2_b + (size_t)j*O_, out + (size_t)(1+j)*512*O_); }
    }
  }

  // main merger (post=False: LN over 1280, then reshape to 512x5120)
  ln_k<<<S_, B256, 0, stream>>>(h, m_ln_w, m_ln_b, aln, E_);
  { Gemm2P pp = mk(aln, mf1B, ffn, nullptr, H4_, H4_, H4_, 512, H4_, H4_);
    pp.part = part; pp.kSplit = 4;
    gemm2_k<0,false,false,true><<<G(512,H4_,4),B256,0,stream>>>(pp);
    reduce_k<2,false,false><<<RG((long long)512*H4_),B256,0,stream>>>(part, 4, (long long)512*H4_, H4_, m_fc1_b, ffn); }
  { Gemm2P pp = mk(ffn, mf2B, out, nullptr, H4_, H4_, O_, 512, O_, H4_);
    pp.part = part; pp.kSplit = 8;
    gemm2_k<0,false,true,true><<<G(512,O_,8),B256,0,stream>>>(pp);
    reduce_k<0,false,true><<<RG((long long)512*O_),B256,0,stream>>>(part, 8, (long long)512*O_, O_, m_fc2_b, out); }
}

// Round 4
// 1634.877 us; speedup vs baseline: 2.8623x; 1.1042x over previous
//
#include <hip/hip_runtime.h>
#include <hip/hip_bf16.h>
#include <cstdio>
#include <cstdint>

// ---------------- model dims ----------------
#define E_    1280
#define L_    4
#define NH_   16
#define D_    80
#define DP_   96      // D padded to mult of 32 for QK^T K-loop
#define MLP_  5120
#define O_    2048
#define S_    2048
#define H4_   5120
#define INP_  1536

typedef __attribute__((ext_vector_type(4))) float f32x4;
typedef __attribute__((ext_vector_type(8))) short short8v;
typedef __attribute__((ext_vector_type(4))) short short4v;

__device__ __forceinline__ short f2bf(float f){
  uint32_t u = __float_as_uint(f);
  uint32_t r = (u + 0x7FFFu + ((u >> 16) & 1u)) >> 16;   // RNE
  return (short)r;
}
__device__ __forceinline__ float bf2f(short s){
  return __uint_as_float(((uint32_t)(uint16_t)s) << 16);
}
__device__ __forceinline__ float gelu_tanh(float x){
  return 0.5f*x*(1.f + tanhf(0.7978845608028654f*(x + 0.044715f*x*x*x)));
}
__device__ __forceinline__ float gelu_erf(float x){
  return 0.5f*x*(1.f + erff(x*0.7071067811865476f));
}
// token -> (h,w) grid coords after the MS=2 window reorder
__device__ __forceinline__ void token_hw(int t, int& hc, int& wc){
  hc = ((t>>1)&1) + ((t>>6)<<1);
  wc = (t&1)      + (((t>>2)&15)<<1);
}

// async global->LDS, 16B per lane; lds dest is wave-uniform base + lane*16
__device__ __forceinline__ void gload16(const short* g, short* l){
  __builtin_amdgcn_global_load_lds((const __attribute__((address_space(1))) void*)g,
                                   (__attribute__((address_space(3))) void*)l, 16, 0, 0);
}

// ---------------- f32 -> bf16 bulk convert ----------------
__global__ __launch_bounds__(256)
void cvt_k(const float* __restrict__ src, short* __restrict__ dst, long long n)
{
  const long long stride = (long long)gridDim.x*256*8;
  for (long long i = ((long long)blockIdx.x*256 + threadIdx.x)*8; i < n; i += stride){
    if (i + 8 <= n){
      float4 v0 = *(const float4*)(src+i);
      float4 v1 = *(const float4*)(src+i+4);
      short8v w;
      w[0]=f2bf(v0.x); w[1]=f2bf(v0.y); w[2]=f2bf(v0.z); w[3]=f2bf(v0.w);
      w[4]=f2bf(v1.x); w[5]=f2bf(v1.y); w[6]=f2bf(v1.z); w[7]=f2bf(v1.w);
      *(short8v*)(dst+i) = w;
    } else {
      for (long long j=i;j<n;j++) dst[j] = f2bf(src[j]);
    }
  }
}

// ---------------- GEMM: bf16, 3-buffer ring, counted vmcnt, optional split-K ----------------
// C[m][n] = epi( sum_k A[m][k]*B[n][k] + bias[n] ) (+ residual from C)
// A:(M,K) bf16 row-major, B:(N,K) bf16 row-major. K % 32 == 0 (and % (32*kSplit) for split).
struct Gemm2P {
  const short* A; const short* B; void* C;
  const float* bias;
  float* part;                  // split-K partial buffer [kSplit][M][N] f32
  int lda, ldb, ldc, M, N, K;
  float scale;
  long long aOffH, aOffI, bOffH, bOffI, cOffH, cOffI;
  int nImg, kSplit;
};

template<int EPI, bool RES, bool CF32, bool SPLIT>   // EPI: 0=none,1=gelu_tanh,2=gelu_erf,3=scale
__global__ __launch_bounds__(256)
void gemm2_k(Gemm2P p)
{
  __shared__ short As[3][4096];   // [buf][128*32]
  __shared__ short Bs[3][4096];

  int z = blockIdx.z, ks = 0;
  if constexpr (SPLIT){ ks = z % p.kSplit; z /= p.kSplit; }
  const int hI = z / p.nImg, iI = z % p.nImg;
  const long long aB = (long long)hI*p.aOffH + (long long)iI*p.aOffI;
  const long long bB = (long long)hI*p.bOffH + (long long)iI*p.bOffI;
  const long long cB = (long long)hI*p.cOffH + (long long)iI*p.cOffI;

  // bijective XCD swizzle on the tile plane (m204)
  const int nwg = gridDim.x*gridDim.y;
  const int orig = blockIdx.y*gridDim.x + blockIdx.x;
  const int q8 = nwg >> 3, r8 = nwg & 7;
  const int xcd = orig & 7, oidx = orig >> 3;
  const int wg = (xcd < r8 ? xcd*(q8+1) : r8*(q8+1) + (xcd-r8)*q8) + oidx;
  const int nt = wg % gridDim.x, mt = wg / gridDim.x;

  const int tid = threadIdx.x, lane = tid & 63, wv = tid >> 6;

  // staging: wave wv owns segments (wv*2, wv*2+1); lane l -> row s*16 + l/4, col (l%4)*8
  const int sr = lane >> 2;
  const int sc = (lane & 3) * 8;
  const int Kp  = SPLIT ? p.K / p.kSplit : p.K;
  const int kBeg = SPLIT ? ks * Kp : 0;
  int ra0 = mt*128 + (wv*2+0)*16 + sr; if (ra0 >= p.M) ra0 = p.M-1;
  int ra1 = mt*128 + (wv*2+1)*16 + sr; if (ra1 >= p.M) ra1 = p.M-1;
  int rb0 = nt*128 + (wv*2+0)*16 + sr; if (rb0 >= p.N) rb0 = p.N-1;
  int rb1 = nt*128 + (wv*2+1)*16 + sr; if (rb1 >= p.N) rb1 = p.N-1;
  const short* pa0 = p.A + aB + (long long)ra0*p.lda + sc + kBeg;
  const short* pa1 = p.A + aB + (long long)ra1*p.lda + sc + kBeg;
  const short* pb0 = p.B + bB + (long long)rb0*p.ldb + sc + kBeg;
  const short* pb1 = p.B + bB + (long long)rb1*p.ldb + sc + kBeg;
  const int so0 = (wv*2+0)*512;
  const int so1 = (wv*2+1)*512;

  const int fr = lane & 15, fo = (lane >> 4) * 8;
  const int wr = (wv >> 1) * 64, wc = (wv & 1) * 64;

  f32x4 acc[4][4] = {};

  auto stage = [&](int buf, int t){
    const int k0 = t << 5;
    gload16(pa0 + k0, &As[buf][so0]);
    gload16(pa1 + k0, &As[buf][so1]);
    gload16(pb0 + k0, &Bs[buf][so0]);
    gload16(pb1 + k0, &Bs[buf][so1]);
  };

  const int ntile = Kp >> 5;
  stage(0, 0);
  if (ntile > 1) stage(1, 1);
  for (int t = 0; t < ntile; t++){
    const int cur = t % 3;
    // wait for our own stage(t) loads; leave stage(t+1)'s 4 in flight
    if (t + 1 < ntile) { asm volatile("s_waitcnt vmcnt(4)" ::: "memory"); }
    else               { asm volatile("s_waitcnt vmcnt(0)" ::: "memory"); }
    __builtin_amdgcn_s_barrier();        // all waves' tile-t data now in LDS
    asm volatile("" ::: "memory");
    short8v a[4], b[4];
    #pragma unroll
    for (int i=0;i<4;i++){
      a[i] = *(const short8v*)&As[cur][(wr + i*16 + fr)*32 + fo];
      b[i] = *(const short8v*)&Bs[cur][(wc + i*16 + fr)*32 + fo];
    }
    #pragma unroll
    for (int i=0;i<4;i++)
      #pragma unroll
      for (int j=0;j<4;j++)
        acc[i][j] = __builtin_amdgcn_mfma_f32_16x16x32_bf16(a[i], b[j], acc[i][j], 0, 0, 0);
    if (t + 2 < ntile) stage((t+2)%3, t+2);   // buf was last read at t-1; all waves past barrier(t)
  }

  #pragma unroll
  for (int i=0;i<4;i++){
    #pragma unroll
    for (int j=0;j<4;j++){
      #pragma unroll
      for (int r=0;r<4;r++){
        const int row = mt*128 + wr + i*16 + (lane>>4)*4 + r;
        const int col = nt*128 + wc + j*16 + fr;
        if (row < p.M && col < p.N){
          float v = acc[i][j][r];
          if constexpr (SPLIT){
            p.part[((long long)ks*p.M + row)*p.N + col] = v;   // raw partial
          } else {
            if (p.bias) v += p.bias[col];
            if constexpr (EPI==1) v = gelu_tanh(v);
            if constexpr (EPI==2) v = gelu_erf(v);
            if constexpr (EPI==3) v *= p.scale;
            const long long off = cB + (long long)row*p.ldc + col;
            if constexpr (RES)  v += ((const float*)p.C)[off];
            if constexpr (CF32) ((float*)p.C)[off] = v;
            else                ((short*)p.C)[off] = f2bf(v);
          }
        }
      }
    }
  }
}

// ---------------- split-K reduce (C contiguous, ldc == N) ----------------
template<int EPI, bool RES, bool CF32>
__global__ __launch_bounds__(256)
void reduce_k(const float* __restrict__ part, int kSplit, long long MN, int N,
              const float* __restrict__ bias, void* __restrict__ C)
{
  const long long i = ((long long)blockIdx.x*256 + threadIdx.x)*4;
  if (i >= MN) return;
  float4 s = *(const float4*)(part + i);
  for (int ks = 1; ks < kSplit; ks++){
    const float4 v = *(const float4*)(part + (long long)ks*MN + i);
    s.x += v.x; s.y += v.y; s.z += v.z; s.w += v.w;
  }
  if (bias){
    const int col = (int)(i % N);
    const float4 b = *(const float4*)(bias + col);
    s.x += b.x; s.y += b.y; s.z += b.z; s.w += b.w;
  }
  if constexpr (EPI==1){ s.x=gelu_tanh(s.x); s.y=gelu_tanh(s.y); s.z=gelu_tanh(s.z); s.w=gelu_tanh(s.w); }
  if constexpr (EPI==2){ s.x=gelu_erf(s.x);  s.y=gelu_erf(s.y);  s.z=gelu_erf(s.z);  s.w=gelu_erf(s.w); }
  if constexpr (RES){
    const float4 r = *(const float4*)((const float*)C + i);
    s.x += r.x; s.y += r.y; s.z += r.z; s.w += r.w;
  }
  if constexpr (CF32){
    *(float4*)((float*)C + i) = s;
  } else {
    short4v o; o[0]=f2bf(s.x); o[1]=f2bf(s.y); o[2]=f2bf(s.z); o[3]=f2bf(s.w);
    *(short4v*)((short*)C + i) = o;
  }
}

// ---------------- fused flash attention ----------------
// grid (8 qtiles, 16 heads, 2 imgs), 256 threads (4 waves x 32 q-rows).
// qh/kh: [NH][S][96] bf16 (cols 80..95 zero); vt: [NH][img][80][1024] bf16.
// out o2: [S][E] bf16 at col h*80.
__global__ __launch_bounds__(256)
void fattn_k(const short* __restrict__ qh, const short* __restrict__ kh,
             const short* __restrict__ vt, short* __restrict__ o2)
{
  __shared__ short Ks[2][13312];   // [buf][128 rows][104]  (208B rows: conflict-free)
  __shared__ short Vs[2][12288];   // [buf][80 rows][152]   (304B rows: conflict-free)
  __shared__ short Ps[17408];      // [128][136]            (272B rows: conflict-free)

  const int qt = blockIdx.x, h = blockIdx.y, img = blockIdx.z;
  const int tid = threadIdx.x, lane = tid & 63, wv = tid >> 6;
  const int fr = lane & 15, fo = (lane >> 4) * 8, g = lane >> 4;
  const int wr = wv * 32;

  const short* qp = qh + ((long long)h*S_ + img*1024 + qt*128)*DP_;
  const short* kp = kh + ((long long)h*S_ + img*1024)*DP_;
  const short* vp = vt + ((long long)(h*2 + img))*80*1024;

  // Q fragments in registers (rows wr+i*16+fr)
  short8v q[2][3];
  #pragma unroll
  for (int i=0;i<2;i++)
    #pragma unroll
    for (int t3=0;t3<3;t3++)
      q[i][t3] = *(const short8v*)(qp + (long long)(wr + i*16 + fr)*DP_ + t3*32 + fo);

  // staging maps (per-lane linear-LDS -> (row,col)); K tile 26624B, V tile 24576B (incl pad)
  int rK[7], cK[7], rV[6], cV[6];
  #pragma unroll
  for (int it=0; it<7; it++){
    const int o = it*4096 + tid*16;
    int r = o / 208, c = o % 208;
    if (c >= 192) c = 0;            // pad cols: harmless duplicate
    rK[it] = r; cK[it] = c >> 1;
  }
  #pragma unroll
  for (int it=0; it<6; it++){
    const int o = it*4096 + tid*16;
    int r = o / 304, c = o % 304;
    if (r >= 80){ r = 0; c = 0; }   // rounding pad
    if (c >= 256) c = 0;
    rV[it] = r; cV[it] = c >> 1;
  }

  auto stage = [&](int b, int t){
    #pragma unroll
    for (int it=0; it<7; it++)
      if (it*4 + wv < 26)           // 26624B = 26 wave-chunks (wave-uniform guard)
        gload16(kp + (long long)(t*128 + rK[it])*DP_ + cK[it], &Ks[b][it*2048 + wv*512]);
    #pragma unroll
    for (int it=0; it<6; it++)      // 24576B = 24 wave-chunks exactly
      gload16(vp + (long long)rV[it]*1024 + t*128 + cV[it], &Vs[b][it*2048 + wv*512]);
  };

  float m_[2][4], l_[2][4];
  f32x4 ao[2][5] = {};
  #pragma unroll
  for (int i=0;i<2;i++)
    #pragma unroll
    for (int r=0;r<4;r++){ m_[i][r] = -3.0e38f; l_[i][r] = 0.f; }

  stage(0, 0);
  __syncthreads();

  for (int t = 0; t < 8; t++){
    const int b = t & 1;
    if (t < 7) stage(b^1, t+1);     // overlaps whole tile; drained by end-of-tile barrier

    // S = Q @ K^T  (rows wr..wr+31 per wave, cols 0..127)
    f32x4 sc[2][8] = {};
    #pragma unroll
    for (int j=0;j<8;j++){
      #pragma unroll
      for (int t3=0;t3<3;t3++){
        const short8v kb = *(const short8v*)&Ks[b][(j*16+fr)*104 + t3*32 + fo];
        sc[0][j] = __builtin_amdgcn_mfma_f32_16x16x32_bf16(q[0][t3], kb, sc[0][j], 0,0,0);
        sc[1][j] = __builtin_amdgcn_mfma_f32_16x16x32_bf16(q[1][t3], kb, sc[1][j], 0,0,0);
      }
    }
    #pragma unroll
    for (int i=0;i<2;i++)
      #pragma unroll
      for (int j=0;j<8;j++)
        sc[i][j] *= 0.11180339887498949f;

    // online softmax; rows are lane-group-local (16 fr-lanes per row)
    #pragma unroll
    for (int i=0;i<2;i++){
      #pragma unroll
      for (int r=0;r<4;r++){
        float mx = sc[i][0][r];
        #pragma unroll
        for (int j=1;j<8;j++) mx = fmaxf(mx, sc[i][j][r]);
        mx = fmaxf(mx, __shfl_xor(mx, 1, 64));
        mx = fmaxf(mx, __shfl_xor(mx, 2, 64));
        mx = fmaxf(mx, __shfl_xor(mx, 4, 64));
        mx = fmaxf(mx, __shfl_xor(mx, 8, 64));
        const float mn = fmaxf(m_[i][r], mx);
        const float al = __expf(m_[i][r] - mn);
        float ts = 0.f;
        #pragma unroll
        for (int j=0;j<8;j++){
          const float pv = __expf(sc[i][j][r] - mn);
          sc[i][j][r] = pv;
          ts += pv;
        }
        ts += __shfl_xor(ts, 1, 64);
        ts += __shfl_xor(ts, 2, 64);
        ts += __shfl_xor(ts, 4, 64);
        ts += __shfl_xor(ts, 8, 64);
        l_[i][r] = l_[i][r]*al + ts;
        m_[i][r] = mn;
        #pragma unroll
        for (int n=0;n<5;n++) ao[i][n][r] *= al;
        // write P row (wave-local region of Ps)
        const int row = wr + i*16 + g*4 + r;
        #pragma unroll
        for (int j=0;j<8;j++) Ps[row*136 + j*16 + fr] = f2bf(sc[i][j][r]);
      }
    }

    // O += P @ V   (P re-read in A-layout: wave-local rows, no barrier needed)
    #pragma unroll
    for (int t4=0;t4<4;t4++){
      short8v pa0 = *(const short8v*)&Ps[(wr + 0  + fr)*136 + t4*32 + fo];
      short8v pa1 = *(const short8v*)&Ps[(wr + 16 + fr)*136 + t4*32 + fo];
      #pragma unroll
      for (int n=0;n<5;n++){
        const short8v vb = *(const short8v*)&Vs[b][(n*16+fr)*152 + t4*32 + fo];
        ao[0][n] = __builtin_amdgcn_mfma_f32_16x16x32_bf16(pa0, vb, ao[0][n], 0,0,0);
        ao[1][n] = __builtin_amdgcn_mfma_f32_16x16x32_bf16(pa1, vb, ao[1][n], 0,0,0);
      }
    }
    __syncthreads();   // drains stage(t+1); fences K/V buffer reuse + next P overwrite
  }

  short* op = o2 + ((long long)(img*1024 + qt*128))*E_ + h*80;
  #pragma unroll
  for (int i=0;i<2;i++){
    #pragma unroll
    for (int r=0;r<4;r++){
      const float inv = 1.f / l_[i][r];
      const int row = wr + i*16 + g*4 + r;
      #pragma unroll
      for (int n=0;n<5;n++)
        op[(long long)row*E_ + n*16 + fr] = f2bf(ao[i][n][r] * inv);
    }
  }
}

// ---------------- LayerNorm (f32 in, bf16 out) ----------------
__global__ __launch_bounds__(256)
void ln_k(const float* __restrict__ X, const float* __restrict__ g, const float* __restrict__ bta,
          short* __restrict__ Y, int Cn)
{
  __shared__ float red[8];
  const int row = blockIdx.x;
  const float* x = X + (long long)row*Cn;
  short* y = Y + (long long)row*Cn;
  float s = 0.f, sq = 0.f;
  for (int c = threadIdx.x*4; c < Cn; c += 1024){
    float4 v = *(const float4*)(x + c);
    s  += v.x+v.y+v.z+v.w;
    sq += v.x*v.x+v.y*v.y+v.z*v.z+v.w*v.w;
  }
  #pragma unroll
  for (int m=32;m;m>>=1){ s += __shfl_xor(s,m,64); sq += __shfl_xor(sq,m,64); }
  const int wv = threadIdx.x>>6, lane = threadIdx.x&63;
  if (lane==0){ red[wv]=s; red[4+wv]=sq; }
  __syncthreads();
  s  = red[0]+red[1]+red[2]+red[3];
  sq = red[4]+red[5]+red[6]+red[7];
  const float mean = s / (float)Cn;
  const float var  = sq / (float)Cn - mean*mean;
  const float rs   = rsqrtf(var + 1e-6f);
  for (int c = threadIdx.x*4; c < Cn; c += 1024){
    float4 v  = *(const float4*)(x + c);
    float4 gw = *(const float4*)(g + c);
    float4 bw = *(const float4*)(bta + c);
    short4v o;
    o[0] = f2bf((v.x-mean)*rs*gw.x + bw.x);
    o[1] = f2bf((v.y-mean)*rs*gw.y + bw.y);
    o[2] = f2bf((v.z-mean)*rs*gw.z + bw.z);
    o[3] = f2bf((v.w-mean)*rs*gw.w + bw.w);
    *(short4v*)(y + c) = o;
  }
}

// ---------------- rope + head layout (bf16 qkv in) ----------------
// qh/kh: [NH][S][96] (cols 80..95 zero-padded); vt: [NH][img][80][1024]
__global__ __launch_bounds__(256)
void rope_k(const short* __restrict__ qkv, short* __restrict__ qh,
            short* __restrict__ kh, short* __restrict__ vt)
{
  const int idx = blockIdx.x*256 + threadIdx.x;     // over S*NH*40
  if (idx >= S_*NH_*40) return;
  const int d0 = idx % 40;
  const int h  = (idx / 40) % NH_;
  const int s  = idx / (40*NH_);
  const int t  = s & 1023, img = s >> 10;
  int hc, wc; token_hw(t, hc, wc);
  const int j  = d0 % 20;
  const float invf = exp2f(-0.66438561897747f * (float)j);   // 10000^(-j/20)
  const float pos  = (float)((d0 < 20) ? hc : wc);
  float sn, cs; sincosf(pos * invf, &sn, &cs);
  const short* base = qkv + (long long)s*3840 + h*80;
  const float q1 = bf2f(base[d0]),      q2 = bf2f(base[d0+40]);
  const float k1 = bf2f(base[1280+d0]), k2 = bf2f(base[1280+d0+40]);
  const long long qo = ((long long)h*S_ + s)*DP_;
  qh[qo + d0]    = f2bf(q1*cs - q2*sn);
  qh[qo + d0+40] = f2bf(q2*cs + q1*sn);
  kh[qo + d0]    = f2bf(k1*cs - k2*sn);
  kh[qo + d0+40] = f2bf(k2*cs + k1*sn);
  if (d0 < 16){ qh[qo + 80 + d0] = 0; kh[qo + 80 + d0] = 0; }
  const long long vo = (((long long)h*2 + img)*80)*1024 + t;
  vt[vo + (long long)d0*1024]      = base[2560+d0];
  vt[vo + (long long)(d0+40)*1024] = base[2560+d0+40];
}

// ---------------- pos-embed bilinear interpolation add ----------------
__global__ __launch_bounds__(256)
void posadd_k(float* __restrict__ h, const float* __restrict__ pe)
{
  const int idx = blockIdx.x*256 + threadIdx.x;     // over S*(E/4)
  if (idx >= S_*(E_/4)) return;
  const int c4 = idx % (E_/4), s = idx / (E_/4);
  const int e = c4*4;
  const int t = s & 1023;
  int hc, wc; token_hw(t, hc, wc);
  const float hi = (float)hc * (47.f/31.f);
  const float wi = (float)wc * (47.f/31.f);
  int hf = (int)hi; float dh = hi - (float)hf; int h2 = min(hf+1, 47);
  int wf = (int)wi; float dw = wi - (float)wf; int w2 = min(wf+1, 47);
  const float w00=(1.f-dh)*(1.f-dw), w01=(1.f-dh)*dw, w10=dh*(1.f-dw), w11=dh*dw;
  const float4 a = *(const float4*)(pe + ((long long)(hf*48+wf))*E_ + e);
  const float4 b = *(const float4*)(pe + ((long long)(hf*48+w2))*E_ + e);
  const float4 c = *(const float4*)(pe + ((long long)(h2*48+wf))*E_ + e);
  const float4 d = *(const float4*)(pe + ((long long)(h2*48+w2))*E_ + e);
  float* out = h + (long long)s*E_ + e;
  float4 o = *(float4*)out;
  o.x += w00*a.x + w01*b.x + w10*c.x + w11*d.x;
  o.y += w00*a.y + w01*b.y + w10*c.y + w11*d.y;
  o.z += w00*a.z + w01*b.z + w10*c.z + w11*d.z;
  o.w += w00*a.w + w01*b.w + w10*c.w + w11*d.w;
  *(float4*)out = o;
}

// ---------------- host side ----------------
static Gemm2P mk(const short* A, const short* B, void* C, const float* bias,
                 int lda, int ldb, int ldc, int M, int N, int K, float scale = 1.f)
{
  Gemm2P p{}; p.A=A; p.B=B; p.C=C; p.bias=bias; p.part=nullptr;
  p.lda=lda; p.ldb=ldb; p.ldc=ldc; p.M=M; p.N=N; p.K=K; p.scale=scale;
  p.aOffH=p.aOffI=p.bOffH=p.bOffI=p.cOffH=p.cOffI=0; p.nImg=1; p.kSplit=1;
  return p;
}

extern "C" void kernel_launch(void* const* d_in, const int* in_sizes, int n_in,
                              void* d_out, int out_size, void* d_ws, size_t ws_size,
                              hipStream_t stream)
{
  const float* x           = (const float*)d_in[0];
  const float* patch_w     = (const float*)d_in[1];
  const float* patch_b     = (const float*)d_in[2];
  const float* pos_emb     = (const float*)d_in[3];
  const float* ln1_w       = (const float*)d_in[4];
  const float* ln1_b       = (const float*)d_in[5];
  const float* ln2_w       = (const float*)d_in[6];
  const float* ln2_b       = (const float*)d_in[7];
  const float* qkv_w       = (const float*)d_in[8];
  const float* qkv_b       = (const float*)d_in[9];
  const float* attn_proj_w = (const float*)d_in[10];
  const float* attn_proj_b = (const float*)d_in[11];
  const float* fc1_w       = (const float*)d_in[12];
  const float* fc1_b       = (const float*)d_in[13];
  const float* fc2_w       = (const float*)d_in[14];
  const float* fc2_b       = (const float*)d_in[15];
  const float* m_ln_w      = (const float*)d_in[16];
  const float* m_ln_b      = (const float*)d_in[17];
  const float* m_fc1_w     = (const float*)d_in[18];
  const float* m_fc1_b     = (const float*)d_in[19];
  const float* m_fc2_w     = (const float*)d_in[20];
  const float* m_fc2_b     = (const float*)d_in[21];
  const float* ds_ln_w     = (const float*)d_in[22];
  const float* ds_ln_b     = (const float*)d_in[23];
  const float* ds_fc1_w    = (const float*)d_in[24];
  const float* ds_fc1_b    = (const float*)d_in[25];
  const float* ds_fc2_w    = (const float*)d_in[26];
  const float* ds_fc2_b    = (const float*)d_in[27];
  float* out = (float*)d_out;

  char* wsp = (char*)d_ws;
  auto alloc = [&](size_t bytes)->char*{
    char* p = wsp; wsp += (bytes + 255) & ~(size_t)255; return p;
  };
  // activations
  float* h    = (float*)alloc((size_t)S_*E_*4);         // residual stream (f32)
  short* qkvb = (short*)alloc((size_t)S_*3840*2);       // qkv proj out (bf16)
  short* aln  = (short*)alloc((size_t)S_*E_*2);         // LN out (bf16); merger LN reuses
  short* qh   = (short*)alloc((size_t)NH_*S_*DP_*2);    // [NH][S][96]
  short* kh   = (short*)alloc((size_t)NH_*S_*DP_*2 + 4096);
  short* vt   = (short*)alloc((size_t)NH_*2*D_*1024*2 + 4096); // [NH][img][80][1024]
  float* part = (float*)alloc((size_t)48*1024*1024);    // split-K partials
  short* o2   = (short*)alloc((size_t)S_*E_*2);         // attn out token-major (bf16)
  short* ffn  = (short*)alloc((size_t)S_*MLP_*2);       // gelu(fc1) out; merger mid reuses
  // bf16 weight cache
  short* xb    = (short*)alloc((size_t)S_*INP_*2);
  short* pwB   = (short*)alloc((size_t)E_*INP_*2);
  short* qkvwB = (short*)alloc((size_t)L_*3840*E_*2);
  short* prwB  = (short*)alloc((size_t)L_*E_*E_*2);
  short* f1wB  = (short*)alloc((size_t)L_*MLP_*E_*2);
  short* f2wB  = (short*)alloc((size_t)L_*E_*MLP_*2);
  short* mf1B  = (short*)alloc((size_t)H4_*H4_*2);
  short* mf2B  = (short*)alloc((size_t)O_*H4_*2);
  short* df1B  = (short*)alloc((size_t)2*H4_*H4_*2);
  short* df2B  = (short*)alloc((size_t)2*O_*H4_*2);
  size_t need = (size_t)(wsp - (char*)d_ws);
  if (need > ws_size){
    fprintf(stderr, "kernel_launch: ws too small: need %zu have %zu\n", need, ws_size);
    return;
  }

  const dim3 B256(256);
  auto cvt = [&](const float* src, short* dst, long long n){
    unsigned blk = (unsigned)min((long long)8192, (n/8 + 255)/256);
    cvt_k<<<blk, B256, 0, stream>>>(src, dst, n);
  };
  cvt(x, xb, (long long)S_*INP_);
  cvt(patch_w, pwB, (long long)E_*INP_);
  cvt(qkv_w, qkvwB, (long long)L_*3840*E_);
  cvt(attn_proj_w, prwB, (long long)L_*E_*E_);
  cvt(fc1_w, f1wB, (long long)L_*MLP_*E_);
  cvt(fc2_w, f2wB, (long long)L_*E_*MLP_);
  cvt(m_fc1_w, mf1B, (long long)H4_*H4_);
  cvt(m_fc2_w, mf2B, (long long)O_*H4_);
  cvt(ds_fc1_w, df1B, (long long)2*H4_*H4_);
  cvt(ds_fc2_w, df2B, (long long)2*O_*H4_);

  auto G = [](int M, int N, int ks = 1){
    return dim3((unsigned)((N+127)/128), (unsigned)((M+127)/128), (unsigned)ks);
  };
  auto RG = [](long long MN){ return dim3((unsigned)((MN/4 + 255)/256)); };

  // patch embed: h = x @ patch_w^T + patch_b   (split-K x4)
  { Gemm2P pp = mk(xb, pwB, h, nullptr, INP_, INP_, E_, S_, E_, INP_);
    pp.part = part; pp.kSplit = 4;
    gemm2_k<0,false,true,true><<<G(S_,E_,4),B256,0,stream>>>(pp);
    reduce_k<0,false,true><<<RG((long long)S_*E_),B256,0,stream>>>(part, 4, (long long)S_*E_, E_, patch_b, h); }
  posadd_k<<<(S_*(E_/4)+255)/256, B256, 0, stream>>>(h, pos_emb);

  for (int l = 0; l < L_; l++){
    // attention
    ln_k<<<S_, B256, 0, stream>>>(h, ln1_w + l*E_, ln1_b + l*E_, aln, E_);
    { Gemm2P pp = mk(aln, qkvwB + (size_t)l*3840*E_, qkvb, qkv_b + l*3840, E_, E_, 3840, S_, 3840, E_);
      gemm2_k<0,false,false,false><<<G(S_,3840),B256,0,stream>>>(pp); }
    rope_k<<<(S_*NH_*40+255)/256, B256, 0, stream>>>(qkvb, qh, kh, vt);
    fattn_k<<<dim3(8,16,2), B256, 0, stream>>>(qh, kh, vt, o2);
    // attn proj (+residual): split-K x4
    { Gemm2P pp = mk(o2, prwB + (size_t)l*E_*E_, h, nullptr, E_, E_, E_, S_, E_, E_);
      pp.part = part; pp.kSplit = 4;
      gemm2_k<0,false,true,true><<<G(S_,E_,4),B256,0,stream>>>(pp);
      reduce_k<0,true,true><<<RG((long long)S_*E_),B256,0,stream>>>(part, 4, (long long)S_*E_, E_, attn_proj_b + l*E_, h); }

    // MLP
    ln_k<<<S_, B256, 0, stream>>>(h, ln2_w + l*E_, ln2_b + l*E_, aln, E_);
    { Gemm2P pp = mk(aln, f1wB + (size_t)l*MLP_*E_, ffn, fc1_b + l*MLP_, E_, E_, MLP_, S_, MLP_, E_);
      gemm2_k<1,false,false,false><<<G(S_,MLP_),B256,0,stream>>>(pp); }
    // fc2 (+residual): split-K x4
    { Gemm2P pp = mk(ffn, f2wB + (size_t)l*E_*MLP_, h, nullptr, MLP_, MLP_, E_, S_, E_, MLP_);
      pp.part = part; pp.kSplit = 4;
      gemm2_k<0,false,true,true><<<G(S_,E_,4),B256,0,stream>>>(pp);
      reduce_k<0,true,true><<<RG((long long)S_*E_),B256,0,stream>>>(part, 4, (long long)S_*E_, E_, fc2_b + l*E_, h); }

    // deepstack mergers after layers 1 and 2 (post=True: reshape then LN over 5120)
    if (l == 1 || l == 2){
      const int j = l - 1;
      ln_k<<<512, B256, 0, stream>>>(h, ds_ln_w + (size_t)j*H4_, ds_ln_b + (size_t)j*H4_, aln, H4_);
      { Gemm2P pp = mk(aln, df1B + (size_t)j*H4_*H4_, ffn, nullptr, H4_, H4_, H4_, 512, H4_, H4_);
        pp.part = part; pp.kSplit = 4;
        gemm2_k<0,false,false,true><<<G(512,H4_,4),B256,0,stream>>>(pp);
        reduce_k<2,false,false><<<RG((long long)512*H4_),B256,0,stream>>>(part, 4, (long long)512*H4_, H4_, ds_fc1_b + (size_t)j*H4_, ffn); }
      { Gemm2P pp = mk(ffn, df2B + (size_t)j*O_*H4_, out + (size_t)(1+j)*512*O_, nullptr, H4_, H4_, O_, 512, O_, H4_);
        pp.part = part; pp.kSplit = 8;
        gemm2_k<0,false,true,true><<<G(512,O_,8),B256,0,stream>>>(pp);
        reduce_k<0,false,true><<<RG((long long)512*O_),B256,0,stream>>>(part, 8, (long long)512*O_, O_, ds_fc2_b + (size_t)j*O_, out + (size_t)(1+j)*512*O_); }
    }
  }

  // main merger (post=False: LN over 1280, then reshape to 512x5120)
  ln_k<<<S_, B256, 0, stream>>>(h, m_ln_w, m_ln_b, aln, E_);
  { Gemm2P pp = mk(aln, mf1B, ffn, nullptr, H4_, H4_, H4_, 512, H4_, H4_);
    pp.part = part; pp.kSplit = 4;
    gemm2_k<0,false,false,true><<<G(512,H4_,4),B256,0,stream>>>(pp);
    reduce_k<2,false,false><<<RG((long long)512*H4_),B256,0,stream>>>(part, 4, (long long)512*H4_, H4_, m_fc1_b, ffn); }
  { Gemm2P pp = mk(ffn, mf2B, out, nullptr, H4_, H4_, O_, 512, O_, H4_);
    pp.part = part; pp.kSplit = 8;
    gemm2_k<0,false,true,true><<<G(512,O_,8),B256,0,stream>>>(pp);
    reduce_k<0,false,true><<<RG((long long)512*O_),B256,0,stream>>>(part, 8, (long long)512*O_, O_, m_fc2_b, out); }
}